// Round 7
// baseline (441.030 us; speedup 1.0000x reference)
//
#include <hip/hip_runtime.h>
#include <cmath>

typedef unsigned short u16;
typedef __bf16 bf16x8 __attribute__((ext_vector_type(8)));
typedef float f32x4 __attribute__((ext_vector_type(4)));
typedef float float4v __attribute__((ext_vector_type(4)));
typedef u16 ushort4v __attribute__((ext_vector_type(4)));
typedef u16 ushort8v __attribute__((ext_vector_type(8)));

#define DIMC 768
#define NP 196
#define MTOT 6272         // 32*196
#define HIDC 3072
#define LAMC 3.5f

__device__ const float C14d[14] = {
  1.0f, 0.9009688679024191f, 0.6234898018587336f, 0.22252093395631445f,
  -0.22252093395631445f, -0.6234898018587336f, -0.9009688679024191f, -1.0f,
  -0.9009688679024191f, -0.6234898018587336f, -0.22252093395631445f,
  0.22252093395631445f, 0.6234898018587336f, 0.9009688679024191f
};
__device__ const float S14d[14] = {
  0.0f, 0.43388373911755823f, 0.7818314824680298f, 0.9749279121818236f,
  0.9749279121818236f, 0.7818314824680298f, 0.43388373911755823f, 0.0f,
  -0.43388373911755823f, -0.7818314824680298f, -0.9749279121818236f,
  -0.9749279121818236f, -0.7818314824680298f, -0.43388373911755823f
};

__device__ __forceinline__ u16 f2bf(float f) {
  unsigned u = __builtin_bit_cast(unsigned, f);
  unsigned r = u + 0x7FFFu + ((u >> 16) & 1u);
  return (u16)(r >> 16);
}
__device__ __forceinline__ float bf2f(u16 u) {
  return __builtin_bit_cast(float, (unsigned)u << 16);
}

typedef const __attribute__((address_space(1))) u16* gas_p;
typedef __attribute__((address_space(3))) u16* las_p;
__device__ __forceinline__ void gl16(const u16* g, u16* l) {
  __builtin_amdgcn_global_load_lds((gas_p)g, (las_p)l, 16, 0, 0);
}

// ---------------- build fragment-ordered DFT matrices F / G ----------------
__global__ __launch_bounds__(256) void initfg_k(u16* __restrict__ Ff, u16* __restrict__ Gf) {
  int idx = blockIdx.x * 256 + threadIdx.x;
  if (idx < 50176) {                       // Ff: 14*7*64*8
    int j = idx & 7, lane = (idx >> 3) & 63;
    int mk = idx >> 9, k0 = mk % 7, m0 = mk / 7;
    int s = m0 * 16 + (lane & 15);
    int q = k0 * 32 + (lane >> 4) * 8 + j;
    float v = 0.f;
    if (q < 196) {
      int kr = s >> 4, f = (s >> 1) & 7, r = q / 14, c = q % 14;
      int th = (kr * r + f * c) % 14;
      v = (s & 1) ? -S14d[th] : C14d[th];
    }
    Ff[idx] = f2bf(v);
  } else if (idx < 50176 + 46592) {        // Gf: 13*7*64*8
    int t = idx - 50176;
    int j = t & 7, lane = (t >> 3) & 63;
    int pk = t >> 9, k0 = pk % 7, p0 = pk / 7;
    int p = p0 * 16 + (lane & 15);
    int s = k0 * 32 + (lane >> 4) * 8 + j;
    float v = 0.f;
    if (p < 196) {
      int kr = s >> 4, f = (s >> 1) & 7, r = p / 14, c = p % 14;
      int th = (kr * r + f * c) % 14;
      float w = (f == 0 || f == 7) ? 1.f : 2.f;
      v = (w * (1.f / 196.f)) * ((s & 1) ? -S14d[th] : C14d[th]);
    }
    Gf[t] = f2bf(v);
  }
}

// ---------------- fused weight convert ----------------
__global__ __launch_bounds__(256) void cvtw_k(
    const float* __restrict__ w0, const float* __restrict__ w1,
    const float* __restrict__ w2, const float* __restrict__ w3,
    u16* __restrict__ o0, u16* __restrict__ o1,
    u16* __restrict__ o2, u16* __restrict__ o3) {
  int idx = blockIdx.x * 256 + threadIdx.x;
  const float* s; u16* d; int base;
  if (idx < 147456)      { s = w0; d = o0; base = 0; }
  else if (idx < 294912) { s = w1; d = o1; base = 147456; }
  else if (idx < 884736) { s = w2; d = o2; base = 294912; }
  else                   { s = w3; d = o3; base = 884736; }
  int i4 = (idx - base) * 4;
  float4v v = *(const float4v*)(s + i4);
  ushort4v o;
#pragma unroll
  for (int j = 0; j < 4; ++j) o[j] = f2bf(v[j]);
  *(ushort4v*)(d + i4) = o;
}

__global__ __launch_bounds__(256) void cvt4_k(const float* __restrict__ s,
                                              u16* __restrict__ d, int n4) {
  int idx = blockIdx.x * 256 + threadIdx.x;
  if (idx >= n4) return;
  int i4 = idx * 4;
  float4v v = *(const float4v*)(s + i4);
  ushort4v o;
#pragma unroll
  for (int j = 0; j < 4; ++j) o[j] = f2bf(v[j]);
  *(ushort4v*)(d + i4) = o;
}

// ---------------- BN-normalize + convert to bf16 ----------------
__global__ __launch_bounds__(256) void bncvt_k(const float* __restrict__ s,
    const float* __restrict__ sc, const float* __restrict__ sh,
    u16* __restrict__ d, int n4) {
  int idx = blockIdx.x * 256 + threadIdx.x;
  if (idx >= n4) return;
  int i4 = idx * 4;
  int c = i4 % DIMC;
  float4v v = *(const float4v*)(s + i4);
  float4v a = *(const float4v*)(sc + c);
  float4v b = *(const float4v*)(sh + c);
  v = v * a + b;
  ushort4v o;
#pragma unroll
  for (int j = 0; j < 4; ++j) o[j] = f2bf(v[j]);
  *(ushort4v*)(d + i4) = o;
}

// ---------------- 256-row 8-wave bf16 MFMA GEMM (T3 2-phase) ----------------
// BM=256, BN=64*NWC, BK=32, 512 threads = 8 waves arranged (8/NWC) x NWC.
// Wave-tile (32*NWC) x 64: cfgA NWC=4 -> 128x64 (acc 128 VGPR, 256 MFMA per
// barrier per block); cfgB NWC=2 -> 64x64 (for fc2's many blocks at K=3072).
// Frag-ordered LDS: chunk c = 16 rows x 32 k (1 KB); in-chunk addr = lane*16B,
// staged by one wave's single gl16 per chunk -> linear, conflict-free reads.
// Loop (T3 minimum, counted vmcnt - never 0 until tail):
//   STAGE(next K-tile) ; s_waitcnt vmcnt(LOADS) ; s_barrier ;
//   ds_read + MFMA on cur ; s_barrier
// EPI 0: f32x4 transpose-write  vxt[(b*768+n)*196+np], m=b*196+np
// EPI 1: f32 C[m*Nr+n] = acc + bias[n] + res[m*Nr+n]
// EPI 2: bf16 C[m*Nr+n] = gelu_exact(acc + bias[n])
template<int EPI, int NWC>
__global__ __launch_bounds__(512, 2) void gemm2_k(
    const u16* __restrict__ A, const u16* __restrict__ Bw,
    const float* __restrict__ bias, const float* __restrict__ res,
    void* __restrict__ Cp, int Nr, int Kr, int ld) {
  constexpr int MBs = 2 * NWC;          // M frags per wave (8 or 4)
  constexpr int BN = 64 * NWC;          // 256 or 128
  constexpr int BCALLS = NWC / 2;       // B stage calls (2 or 1)
  __shared__ __attribute__((aligned(16))) u16 As[2][256 * 32];
  __shared__ __attribute__((aligned(16))) u16 Bs[2][BN * 32];

  const int t = threadIdx.x;
  const int w = t >> 6, lane = t & 63;
  const int l15 = lane & 15, l4 = lane >> 4;
  const int bn = blockIdx.x * BN, bm = blockIdx.y * 256;
  const int wr = w / NWC, wc = w % NWC;

  f32x4 acc[MBs][4];
#pragma unroll
  for (int mb = 0; mb < MBs; ++mb)
#pragma unroll
    for (int nb = 0; nb < 4; ++nb) acc[mb][nb] = (f32x4){0.f, 0.f, 0.f, 0.f};

  // staging source pointers: wave w stages chunk (i*8 + w); 16 rows x 32 k
  const u16* gA[2];
#pragma unroll
  for (int i = 0; i < 2; ++i) {
    int r = bm + (i * 8 + w) * 16 + l15;
    r = r < MTOT ? r : (MTOT - 1);       // clamp M overhang (stores guarded)
    gA[i] = A + (size_t)r * ld + l4 * 8;
  }
  const u16* gB[BCALLS];
#pragma unroll
  for (int i = 0; i < BCALLS; ++i) {
    int r = bn + (i * 8 + w) * 16 + l15;
    gB[i] = Bw + (size_t)r * ld + l4 * 8;
  }

  auto STAGE = [&](int buf, int kt) {
#pragma unroll
    for (int i = 0; i < 2; ++i)
      gl16(gA[i] + kt * 32, &As[buf][(i * 8 + w) * 512]);
#pragma unroll
    for (int i = 0; i < BCALLS; ++i)
      gl16(gB[i] + kt * 32, &Bs[buf][(i * 8 + w) * 512]);
  };

  const int nt = Kr >> 5;
  STAGE(0, 0);
  int cur = 0;
  for (int kt = 0; kt < nt; ++kt) {
    if (kt + 1 < nt) {
      STAGE(cur ^ 1, kt + 1);
      if constexpr (NWC == 4) asm volatile("s_waitcnt vmcnt(4)" ::: "memory");
      else                    asm volatile("s_waitcnt vmcnt(3)" ::: "memory");
    } else {
      asm volatile("s_waitcnt vmcnt(0)" ::: "memory");
    }
    __builtin_amdgcn_s_barrier();
    __builtin_amdgcn_sched_barrier(0);

    bf16x8 af[MBs], bfv[4];
#pragma unroll
    for (int mb = 0; mb < MBs; ++mb)
      af[mb] = *(const bf16x8*)&As[cur][(wr * MBs + mb) * 512 + lane * 8];
#pragma unroll
    for (int nb = 0; nb < 4; ++nb)
      bfv[nb] = *(const bf16x8*)&Bs[cur][(wc * 4 + nb) * 512 + lane * 8];
#pragma unroll
    for (int mb = 0; mb < MBs; ++mb)
#pragma unroll
      for (int nb = 0; nb < 4; ++nb)
        acc[mb][nb] = __builtin_amdgcn_mfma_f32_16x16x32_bf16(af[mb], bfv[nb], acc[mb][nb], 0, 0, 0);

    __builtin_amdgcn_s_barrier();       // all reads of cur done before next STAGE overwrites
    cur ^= 1;
  }

#pragma unroll
  for (int mb = 0; mb < MBs; ++mb) {
#pragma unroll
    for (int nb = 0; nb < 4; ++nb) {
      int n = bn + wc * 64 + nb * 16 + l15;
      int m0 = bm + wr * (32 * NWC) + mb * 16 + l4 * 4;
      if (m0 >= MTOT) continue;
      if (EPI == 0) {
        int bb = m0 / 196, np0 = m0 - bb * 196;   // 4-aligned, same bb for r=0..3
        *(float4v*)&((float*)Cp)[((size_t)bb * DIMC + n) * 196 + np0] =
            (float4v){acc[mb][nb][0], acc[mb][nb][1], acc[mb][nb][2], acc[mb][nb][3]};
      } else {
#pragma unroll
        for (int r = 0; r < 4; ++r) {
          int m = m0 + r;
          float v = acc[mb][nb][r];
          if (EPI == 1) {
            ((float*)Cp)[(size_t)m * Nr + n] = v + bias[n] + res[(size_t)m * Nr + n];
          } else {
            float vb = v + bias[n];
            float ge = 0.5f * vb * (1.f + erff(vb * 0.70710678118654752f));
            ((u16*)Cp)[(size_t)m * Nr + n] = f2bf(ge);
          }
        }
      }
    }
  }
}

// ---------------- BN stats (deterministic 2-stage) ----------------
__global__ __launch_bounds__(256) void stats_part_k(const float* __restrict__ A,
                                                    float* __restrict__ part) {
  int blk = blockIdx.x, t = threadIdx.x;
  float s0a = 0, s0b = 0, s0c = 0, s1a = 0, s1b = 0, s1c = 0;
  const float* base = A + (size_t)blk * 64 * DIMC;
  for (int r = 0; r < 64; ++r) {
    const float* row = base + (size_t)r * DIMC;
    float v0 = row[t], v1 = row[t + 256], v2 = row[t + 512];
    s0a += v0; s1a += v0 * v0;
    s0b += v1; s1b += v1 * v1;
    s0c += v2; s1c += v2 * v2;
  }
  part[(size_t)blk * DIMC + t] = s0a;
  part[(size_t)blk * DIMC + t + 256] = s0b;
  part[(size_t)blk * DIMC + t + 512] = s0c;
  float* p2 = part + 98 * DIMC;
  p2[(size_t)blk * DIMC + t] = s1a;
  p2[(size_t)blk * DIMC + t + 256] = s1b;
  p2[(size_t)blk * DIMC + t + 512] = s1c;
}

__global__ __launch_bounds__(256) void stats_fin_k(const float* __restrict__ part,
    const float* __restrict__ gam, const float* __restrict__ bet,
    float* __restrict__ scale, float* __restrict__ shift) {
  int c = blockIdx.x * 256 + threadIdx.x;
  if (c >= DIMC) return;
  float S = 0.f, Q = 0.f;
  for (int b = 0; b < 98; ++b) {
    S += part[(size_t)b * DIMC + c];
    Q += part[(size_t)(98 + b) * DIMC + c];
  }
  float m = S * (1.0f / 6272.0f);
  float v = Q * (1.0f / 6272.0f) - m * m;
  v = fmaxf(v, 0.f);
  float rs = rsqrtf(v + 1e-5f);
  float sc = gam[c] * rs;
  scale[c] = sc;
  shift[c] = bet[c] - m * sc;
}

// ---------------- MFMA screen: max_i max_p |u_i| per tile, flag > 3.4 ----------
__global__ __launch_bounds__(64) void checkmfma_k(
    const float* __restrict__ vxt, const float* __restrict__ kern,
    const u16* __restrict__ Ff, const u16* __restrict__ Gf,
    int* __restrict__ cnt, int* __restrict__ wl) {
  __shared__ float xf[16 * 228];
  const int lane = threadIdx.x;
  const int wgb = blockIdx.x;
  const int g = wgb >> 1, bhalf = wgb & 1;
  const int tl = lane & 15, h = lane >> 4;
  const float* xbase = vxt + ((size_t)(bhalf * 16 + tl) * DIMC + g) * 196;

  bf16x8 Bx[7];
#pragma unroll
  for (int k0 = 0; k0 < 7; ++k0) {
    int q0 = k0 * 32 + h * 8;
    ushort8v tv;
    if (k0 < 6) {
      float4v f0 = *(const float4v*)(xbase + q0);
      float4v f1 = *(const float4v*)(xbase + q0 + 4);
#pragma unroll
      for (int j = 0; j < 4; ++j) { tv[j] = f2bf(f0[j]); tv[j + 4] = f2bf(f1[j]); }
    } else {
#pragma unroll
      for (int j = 0; j < 8; ++j) {
        int q = q0 + j;
        tv[j] = (q < 196) ? f2bf(xbase[q]) : (u16)0;
      }
    }
    Bx[k0] = __builtin_bit_cast(bf16x8, tv);
  }

  for (int m0 = 0; m0 < 14; ++m0) {
    f32x4 acc = (f32x4){0.f, 0.f, 0.f, 0.f};
#pragma unroll
    for (int k0 = 0; k0 < 7; ++k0) {
      bf16x8 Af = __builtin_bit_cast(bf16x8,
          *(const ushort8v*)(Ff + ((size_t)(m0 * 7 + k0) * 64 + lane) * 8));
      acc = __builtin_amdgcn_mfma_f32_16x16x32_bf16(Af, Bx[k0], acc, 0, 0, 0);
    }
    *(f32x4*)&xf[tl * 228 + m0 * 16 + h * 4] = acc;
  }

  bf16x8 By[5][7];
#pragma unroll
  for (int i = 0; i < 5; ++i) {
    const float* kb = kern + ((size_t)g * 5 + i) * 224;
#pragma unroll
    for (int k0 = 0; k0 < 7; ++k0) {
      f32x4 x0 = *(const f32x4*)&xf[tl * 228 + k0 * 32 + h * 8];
      f32x4 x1 = *(const f32x4*)&xf[tl * 228 + k0 * 32 + h * 8 + 4];
      int mb = k0 * 16 + h * 4;
      float2 ka = *(const float2*)(kb + (mb + 0) * 2);
      float2 kc = *(const float2*)(kb + (mb + 1) * 2);
      float2 ke = *(const float2*)(kb + (mb + 2) * 2);
      float2 kg = *(const float2*)(kb + (mb + 3) * 2);
      ushort8v tv;
      tv[0] = f2bf(ka.x * x0[0] - ka.y * x0[1]);
      tv[1] = f2bf(ka.x * x0[1] + ka.y * x0[0]);
      tv[2] = f2bf(kc.x * x0[2] - kc.y * x0[3]);
      tv[3] = f2bf(kc.x * x0[3] + kc.y * x0[2]);
      tv[4] = f2bf(ke.x * x1[0] - ke.y * x1[1]);
      tv[5] = f2bf(ke.x * x1[1] + ke.y * x1[0]);
      tv[6] = f2bf(kg.x * x1[2] - kg.y * x1[3]);
      tv[7] = f2bf(kg.x * x1[3] + kg.y * x1[2]);
      By[i][k0] = __builtin_bit_cast(bf16x8, tv);
    }
  }

  float vmax = 0.f;
  for (int p0 = 0; p0 < 13; ++p0) {
    f32x4 a0 = (f32x4){0.f, 0.f, 0.f, 0.f};
    f32x4 a1 = a0, a2 = a0, a3 = a0, a4 = a0;
#pragma unroll
    for (int k0 = 0; k0 < 7; ++k0) {
      bf16x8 Ag = __builtin_bit_cast(bf16x8,
          *(const ushort8v*)(Gf + ((size_t)(p0 * 7 + k0) * 64 + lane) * 8));
      a0 = __builtin_amdgcn_mfma_f32_16x16x32_bf16(Ag, By[0][k0], a0, 0, 0, 0);
      a1 = __builtin_amdgcn_mfma_f32_16x16x32_bf16(Ag, By[1][k0], a1, 0, 0, 0);
      a2 = __builtin_amdgcn_mfma_f32_16x16x32_bf16(Ag, By[2][k0], a2, 0, 0, 0);
      a3 = __builtin_amdgcn_mfma_f32_16x16x32_bf16(Ag, By[3][k0], a3, 0, 0, 0);
      a4 = __builtin_amdgcn_mfma_f32_16x16x32_bf16(Ag, By[4][k0], a4, 0, 0, 0);
    }
#pragma unroll
    for (int r = 0; r < 4; ++r) {
      vmax = fmaxf(vmax, fabsf(a0[r]));
      vmax = fmaxf(vmax, fabsf(a1[r]));
      vmax = fmaxf(vmax, fabsf(a2[r]));
      vmax = fmaxf(vmax, fabsf(a3[r]));
      vmax = fmaxf(vmax, fabsf(a4[r]));
    }
  }
  vmax = fmaxf(vmax, __shfl_xor(vmax, 16));
  vmax = fmaxf(vmax, __shfl_xor(vmax, 32));
  if (lane < 16 && vmax > (LAMC - 0.1f)) {
    int idx = atomicAdd(cnt, 1);
    wl[idx] = g * 32 + bhalf * 16 + lane;
  }
}

// ---------------- full ISTA for flagged tiles (fp32, exact) ----------------
__global__ __launch_bounds__(64) void slow_k(
    const float* __restrict__ vxt, const float* __restrict__ kern,
    const float* __restrict__ kern2, const float* __restrict__ Lbuf,
    const int* __restrict__ cnt, const int* __restrict__ wl,
    float* __restrict__ outp) {
  const int t = threadIdx.x;
  __shared__ float TC[196], TSn[196];
  __shared__ float xs[196];
  __shared__ float t1R[112], t1I[112];
  __shared__ float t2R[112], t2I[112];
  __shared__ float zr[112], zi[112];
  __shared__ float kR[5][112], kI[5][112];
  __shared__ float uu[5][196];
  __shared__ float ss[5][196];
  __shared__ float k2R[112], k2I[112];

  for (int i = t; i < 196; i += 64) {
    int a = i / 14, c = i - (i / 14) * 14;
    int m = (a * c) % 14;
    TC[i] = C14d[m]; TSn[i] = S14d[m];
  }
  const int ntile = *cnt;

  auto rowsFwd = [&](const float* xsrc) {
    for (int i = t; i < 112; i += 64) {
      int r = i >> 3, f = i & 7;
      const float* xp = xsrc + r * 14;
      const float* tc = &TC[f * 14]; const float* tsn = &TSn[f * 14];
      float ar = 0.f, ai = 0.f;
#pragma unroll
      for (int c = 0; c < 14; ++c) { float xv = xp[c]; ar += xv * tc[c]; ai -= xv * tsn[c]; }
      t1R[i] = ar; t1I[i] = ai;
    }
    __syncthreads();
  };
  auto colsFwd = [&](float* oR, float* oI) {
    for (int i = t; i < 112; i += 64) {
      int kr = i >> 3, f = i & 7;
      const float* tc = &TC[kr * 14]; const float* tsn = &TSn[kr * 14];
      float br = 0.f, bi = 0.f;
#pragma unroll
      for (int r = 0; r < 14; ++r) {
        float xr = t1R[r * 8 + f], xi = t1I[r * 8 + f];
        br += tc[r] * xr + tsn[r] * xi;
        bi += tc[r] * xi - tsn[r] * xr;
      }
      oR[i] = br; oI[i] = bi;
    }
    __syncthreads();
  };
  auto colsInv = [&]() {
    for (int i = t; i < 112; i += 64) {
      int r = i >> 3, f = i & 7;
      const float* tc = &TC[r * 14]; const float* tsn = &TSn[r * 14];
      float br = 0.f, bi = 0.f;
#pragma unroll
      for (int kr = 0; kr < 14; ++kr) {
        float xr = t1R[kr * 8 + f], xi = t1I[kr * 8 + f];
        br += tc[kr] * xr - tsn[kr] * xi;
        bi += tc[kr] * xi + tsn[kr] * xr;
      }
      t2R[i] = br; t2I[i] = bi;
    }
    __syncthreads();
  };
  auto rowVal = [&](int r, int c) -> float {
    const float* pR = &t2R[r * 8]; const float* pI = &t2I[r * 8];
    float v = pR[0] + ((c & 1) ? -pR[7] : pR[7]);
    float s2 = 0.f;
#pragma unroll
    for (int f = 1; f < 7; ++f) s2 += pR[f] * TC[f * 14 + c] - pI[f] * TSn[f * 14 + c];
    return (v + 2.f * s2) * (1.0f / 196.0f);
  };

  for (int widx = blockIdx.x; widx < ntile; widx += gridDim.x) {
    const int tile = wl[widx];
    const int g = tile >> 5, b = tile & 31;
    __syncthreads();
    for (int i = t; i < 560; i += 64) {
      int ii = i / 112, p = i - ii * 112;
      const float* kp = kern + ((size_t)g * 5 + ii) * 224 + p * 2;
      kR[ii][p] = kp[0]; kI[ii][p] = kp[1];
    }
    for (int i = t; i < 196; i += 64) xs[i] = vxt[((size_t)b * DIMC + g) * 196 + i];
    for (int i = t; i < 112; i += 64) {
      k2R[i] = kern2[(size_t)g * 224 + i * 2];
      k2I[i] = kern2[(size_t)g * 224 + i * 2 + 1];
    }
    __syncthreads();

    rowsFwd(xs);
    colsFwd(zr, zi);
    for (int ii = 0; ii < 5; ++ii) {
      for (int i = t; i < 112; i += 64) {
        float a = kR[ii][i], b2 = kI[ii][i];
        t1R[i] = a * zr[i] - b2 * zi[i];
        t1I[i] = a * zi[i] + b2 * zr[i];
      }
      __syncthreads();
      colsInv();
      for (int i = t; i < 196; i += 64) uu[ii][i] = rowVal(i / 14, i - (i / 14) * 14);
      __syncthreads();
    }

    const float invL = 1.0f / Lbuf[g];
    const float thr = LAMC * invL;
    {
      float* up = &uu[0][0];
      float* sp = &ss[0][0];
      for (int i = t; i < 980; i += 64) {
        float v = up[i];
        float a = fabsf(v) - LAMC;
        sp[i] = a > 0.f ? copysignf(a, v) : 0.f;
      }
    }
    __syncthreads();

    for (int iter = 0; iter < 4; ++iter) {
      for (int i = t; i < 112; i += 64) { zr[i] = 0.f; zi[i] = 0.f; }
      __syncthreads();
      for (int ii = 0; ii < 5; ++ii) {
        rowsFwd(&ss[ii][0]);
        colsFwd(t2R, t2I);
        for (int i = t; i < 112; i += 64) {
          float a = kR[ii][i], b2 = kI[ii][i];
          zr[i] += a * t2R[i] + b2 * t2I[i];
          zi[i] += a * t2I[i] - b2 * t2R[i];
        }
        __syncthreads();
      }
      if (iter == 3) break;
      for (int ii = 0; ii < 5; ++ii) {
        for (int i = t; i < 112; i += 64) {
          float a = kR[ii][i], b2 = kI[ii][i];
          t1R[i] = a * zr[i] - b2 * zi[i];
          t1I[i] = a * zi[i] + b2 * zr[i];
        }
        __syncthreads();
        colsInv();
        for (int i = t; i < 196; i += 64) {
          float v = rowVal(i / 14, i - (i / 14) * 14);
          float sv = ss[ii][i] - (v - uu[ii][i]) * invL;
          float aa = fabsf(sv) - thr;
          ss[ii][i] = aa > 0.f ? copysignf(aa, sv) : 0.f;
        }
        __syncthreads();
      }
    }

    if (t < 28) {
      int kr = t >> 1, f = (t & 1) * 7;
      int d = kr * 8 + f;
      int srci = ((14 - kr) % 14) * 8 + f;
      float pr = 0.5f * (zr[d] + zr[srci]);
      float pi = 0.5f * (zi[d] - zi[srci]);
      zr[d] = pr; zi[d] = pi;
    }
    __syncthreads();
    for (int i = t; i < 112; i += 64) {
      float a = k2R[i], b2 = k2I[i];
      t1R[i] = a * zr[i] - b2 * zi[i];
      t1I[i] = a * zi[i] + b2 * zr[i];
    }
    __syncthreads();
    colsInv();
    for (int i = t; i < 196; i += 64)
      outp[((size_t)(b * 196 + i)) * DIMC + g] = rowVal(i / 14, i - (i / 14) * 14);
  }
}

// ---------------- launch ----------------
extern "C" void kernel_launch(void* const* d_in, const int* in_sizes, int n_in,
                              void* d_out, int out_size, void* d_ws, size_t ws_size,
                              hipStream_t stream) {
  (void)in_sizes; (void)n_in; (void)out_size;
  const float* x      = (const float*)d_in[0];
  const float* v_w    = (const float*)d_in[1];
  const float* proj_w = (const float*)d_in[2];
  const float* proj_b = (const float*)d_in[3];
  const float* kern   = (const float*)d_in[4];
  const float* kern2  = (const float*)d_in[5];
  const float* n1g    = (const float*)d_in[6];
  const float* n1b    = (const float*)d_in[7];
  const float* n2g    = (const float*)d_in[8];
  const float* n2b    = (const float*)d_in[9];
  const float* fc1w   = (const float*)d_in[10];
  const float* fc1b   = (const float*)d_in[11];
  const float* fc2w   = (const float*)d_in[12];
  const float* fc2b   = (const float*)d_in[13];
  const float* Lb     = (const float*)d_in[14];
  float* out = (float*)d_out;

  char* ws = (char*)d_ws;
  size_t o = 0;
  auto alloc = [&](size_t bytes) { size_t r = o; o += (bytes + 255) & ~(size_t)255; return r; };
  u16*   vwbf   = (u16*)(ws + alloc(589824 * 2));
  u16*   projbf = (u16*)(ws + alloc(589824 * 2));
  u16*   fc1bf  = (u16*)(ws + alloc(2359296 * 2));
  u16*   fc2bf  = (u16*)(ws + alloc(2359296 * 2));
  u16*   Ffb    = (u16*)(ws + alloc(50176 * 2));
  u16*   Gfb    = (u16*)(ws + alloc(46592 * 2));
  float* sc1    = (float*)(ws + alloc(768 * 4));
  float* sh1    = (float*)(ws + alloc(768 * 4));
  float* sc2    = (float*)(ws + alloc(768 * 4));
  float* sh2    = (float*)(ws + alloc(768 * 4));
  float* part   = (float*)(ws + alloc(98 * 768 * 2 * 4));
  int*   cnt    = (int*)(ws + alloc(4));
  int*   wl     = (int*)(ws + alloc(24576 * 4));
  u16*   abf    = (u16*)(ws + alloc((size_t)MTOT * DIMC * 2));
  float* vxt    = (float*)(ws + alloc((size_t)MTOT * DIMC * 4));
  float* newm   = (float*)(ws + alloc((size_t)MTOT * DIMC * 4));
  float* new2   = (float*)(ws + alloc((size_t)MTOT * DIMC * 4));
  u16*   hbf    = (u16*)vxt;   // overlay: h (6272x3072 bf16) over vxt+newm (dead by then)
  if (ws_size < o) return;

  hipMemsetAsync(newm, 0, (size_t)MTOT * DIMC * 4, stream);
  hipMemsetAsync(cnt, 0, 4, stream);

  initfg_k<<<378, 256, 0, stream>>>(Ffb, Gfb);
  cvtw_k<<<5760, 256, 0, stream>>>(v_w, proj_w, fc1w, fc2w, vwbf, projbf, fc1bf, fc2bf);
  cvt4_k<<<4704, 256, 0, stream>>>(x, abf, 1204224);

  // vx = x @ v_w^T, transpose-written as (b, g, n)
  gemm2_k<0, 4><<<dim3(3, 25), 512, 0, stream>>>(abf, vwbf, nullptr, nullptr, vxt, DIMC, DIMC, DIMC);
  // MFMA screen -> worklist (newm stays zero for clean tiles)
  checkmfma_k<<<1536, 64, 0, stream>>>(vxt, kern, Ffb, Gfb, cnt, wl);
  // exact ISTA only for flagged tiles
  slow_k<<<1024, 64, 0, stream>>>(vxt, kern, kern2, Lb, cnt, wl, newm);
  // BN1
  stats_part_k<<<98, 256, 0, stream>>>(newm, part);
  stats_fin_k<<<3, 256, 0, stream>>>(part, n1g, n1b, sc1, sh1);
  bncvt_k<<<4704, 256, 0, stream>>>(newm, sc1, sh1, abf, 1204224);
  // new2 = x + BN1(new) @ proj_w^T + proj_b
  gemm2_k<1, 4><<<dim3(3, 25), 512, 0, stream>>>(abf, projbf, proj_b, x, new2, DIMC, DIMC, DIMC);
  // BN2
  stats_part_k<<<98, 256, 0, stream>>>(new2, part);
  stats_fin_k<<<3, 256, 0, stream>>>(part, n2g, n2b, sc2, sh2);
  bncvt_k<<<4704, 256, 0, stream>>>(new2, sc2, sh2, abf, 1204224);
  // h = gelu(BN2(new2) @ fc1^T + fc1_b)
  gemm2_k<2, 4><<<dim3(12, 25), 512, 0, stream>>>(abf, fc1bf, fc1b, nullptr, hbf, HIDC, DIMC, DIMC);
  // out = new2 + h @ fc2^T + fc2_b
  gemm2_k<1, 2><<<dim3(6, 25), 512, 0, stream>>>(hbf, fc2bf, fc2b, new2, out, DIMC, HIDC, HIDC);
}

// Round 8
// 371.819 us; speedup vs baseline: 1.1861x; 1.1861x over previous
//
#include <hip/hip_runtime.h>
#include <cmath>

typedef unsigned short u16;
typedef __bf16 bf16x8 __attribute__((ext_vector_type(8)));
typedef float f32x4 __attribute__((ext_vector_type(4)));
typedef float float4v __attribute__((ext_vector_type(4)));
typedef u16 ushort4v __attribute__((ext_vector_type(4)));
typedef u16 ushort8v __attribute__((ext_vector_type(8)));

#define DIMC 768
#define NP 196
#define MTOT 6272         // 32*196
#define HIDC 3072
#define LAMC 3.5f

__device__ const float C14d[14] = {
  1.0f, 0.9009688679024191f, 0.6234898018587336f, 0.22252093395631445f,
  -0.22252093395631445f, -0.6234898018587336f, -0.9009688679024191f, -1.0f,
  -0.9009688679024191f, -0.6234898018587336f, -0.22252093395631445f,
  0.22252093395631445f, 0.6234898018587336f, 0.9009688679024191f
};
__device__ const float S14d[14] = {
  0.0f, 0.43388373911755823f, 0.7818314824680298f, 0.9749279121818236f,
  0.9749279121818236f, 0.7818314824680298f, 0.43388373911755823f, 0.0f,
  -0.43388373911755823f, -0.7818314824680298f, -0.9749279121818236f,
  -0.9749279121818236f, -0.7818314824680298f, -0.43388373911755823f
};

__device__ __forceinline__ u16 f2bf(float f) {
  unsigned u = __builtin_bit_cast(unsigned, f);
  unsigned r = u + 0x7FFFu + ((u >> 16) & 1u);
  return (u16)(r >> 16);
}
__device__ __forceinline__ float bf2f(u16 u) {
  return __builtin_bit_cast(float, (unsigned)u << 16);
}

typedef const __attribute__((address_space(1))) u16* gas_p;
typedef __attribute__((address_space(3))) u16* las_p;
__device__ __forceinline__ void gl16(const u16* g, u16* l) {
  __builtin_amdgcn_global_load_lds((gas_p)g, (las_p)l, 16, 0, 0);
}

// ---------------- build fragment-ordered DFT matrices F / G ----------------
__global__ __launch_bounds__(256) void initfg_k(u16* __restrict__ Ff, u16* __restrict__ Gf) {
  int idx = blockIdx.x * 256 + threadIdx.x;
  if (idx < 50176) {                       // Ff: 14*7*64*8
    int j = idx & 7, lane = (idx >> 3) & 63;
    int mk = idx >> 9, k0 = mk % 7, m0 = mk / 7;
    int s = m0 * 16 + (lane & 15);
    int q = k0 * 32 + (lane >> 4) * 8 + j;
    float v = 0.f;
    if (q < 196) {
      int kr = s >> 4, f = (s >> 1) & 7, r = q / 14, c = q % 14;
      int th = (kr * r + f * c) % 14;
      v = (s & 1) ? -S14d[th] : C14d[th];
    }
    Ff[idx] = f2bf(v);
  } else if (idx < 50176 + 46592) {        // Gf: 13*7*64*8
    int t = idx - 50176;
    int j = t & 7, lane = (t >> 3) & 63;
    int pk = t >> 9, k0 = pk % 7, p0 = pk / 7;
    int p = p0 * 16 + (lane & 15);
    int s = k0 * 32 + (lane >> 4) * 8 + j;
    float v = 0.f;
    if (p < 196) {
      int kr = s >> 4, f = (s >> 1) & 7, r = p / 14, c = p % 14;
      int th = (kr * r + f * c) % 14;
      float w = (f == 0 || f == 7) ? 1.f : 2.f;
      v = (w * (1.f / 196.f)) * ((s & 1) ? -S14d[th] : C14d[th]);
    }
    Gf[t] = f2bf(v);
  }
}

// ---------------- weight converts ----------------
__global__ __launch_bounds__(256) void cvtw2_k(
    const float* __restrict__ w0, const float* __restrict__ w1,
    u16* __restrict__ o0, u16* __restrict__ o1) {
  int idx = blockIdx.x * 256 + threadIdx.x;
  const float* s; u16* d; int base;
  if (idx < 147456) { s = w0; d = o0; base = 0; }
  else              { s = w1; d = o1; base = 147456; }
  int i4 = (idx - base) * 4;
  float4v v = *(const float4v*)(s + i4);
  ushort4v o;
#pragma unroll
  for (int j = 0; j < 4; ++j) o[j] = f2bf(v[j]);
  *(ushort4v*)(d + i4) = o;
}

__global__ __launch_bounds__(256) void cvt4_k(const float* __restrict__ s,
                                              u16* __restrict__ d, int n4) {
  int idx = blockIdx.x * 256 + threadIdx.x;
  if (idx >= n4) return;
  int i4 = idx * 4;
  float4v v = *(const float4v*)(s + i4);
  ushort4v o;
#pragma unroll
  for (int j = 0; j < 4; ++j) o[j] = f2bf(v[j]);
  *(ushort4v*)(d + i4) = o;
}

// fc1s[n,k] = bf16(fc1w[n,k] * sc2[k])   (BN2 scale folded, single rounding)
__global__ __launch_bounds__(256) void scalefc1_k(const float* __restrict__ w,
    const float* __restrict__ sc, u16* __restrict__ d) {
  int idx = blockIdx.x * 256 + threadIdx.x;
  int i4 = idx * 4;
  int k = i4 % DIMC;
  float4v v = *(const float4v*)(w + i4);
  float4v s = *(const float4v*)(sc + k);
  v = v * s;
  ushort4v o;
#pragma unroll
  for (int j = 0; j < 4; ++j) o[j] = f2bf(v[j]);
  *(ushort4v*)(d + i4) = o;
}

// c0[n] = proj_b[n] + sum_g sh1[g]*projW[n,g]   (n < 768)
__global__ __launch_bounds__(256) void c0_k(const float* __restrict__ projw,
    const float* __restrict__ sh, const float* __restrict__ pb,
    float* __restrict__ c0) {
  int n = blockIdx.x * 256 + threadIdx.x;
  if (n >= DIMC) return;
  const float* row = projw + (size_t)n * DIMC;
  float s = 0.f;
  for (int g = 0; g < DIMC; g += 4) {
    float4v r = *(const float4v*)(row + g);
    float4v h = *(const float4v*)(sh + g);
    s += r[0] * h[0] + r[1] * h[1] + r[2] * h[2] + r[3] * h[3];
  }
  c0[n] = s + pb[n];
}

// d0[n] = fc1b[n] + sum_k sh2[k]*fc1w[n,k]   (n < 3072)
__global__ __launch_bounds__(256) void d0_k(const float* __restrict__ fc1w,
    const float* __restrict__ sh, const float* __restrict__ fb,
    float* __restrict__ d0) {
  int n = blockIdx.x * 256 + threadIdx.x;
  if (n >= HIDC) return;
  const float* row = fc1w + (size_t)n * DIMC;
  float s = 0.f;
  for (int k = 0; k < DIMC; k += 4) {
    float4v r = *(const float4v*)(row + k);
    float4v h = *(const float4v*)(sh + k);
    s += r[0] * h[0] + r[1] * h[1] + r[2] * h[2] + r[3] * h[3];
  }
  d0[n] = s + fb[n];
}

// new2 = x + c0 (dense base); writes f32 + bf16
__global__ __launch_bounds__(256) void base_k(const float* __restrict__ x,
    const float* __restrict__ c0, float* __restrict__ new2,
    u16* __restrict__ new2bf) {
  int idx = blockIdx.x * 256 + threadIdx.x;
  size_t i4 = (size_t)idx * 4;
  int c = (int)(i4 % DIMC);
  float4v v = *(const float4v*)(x + i4);
  float4v a = *(const float4v*)(c0 + c);
  v = v + a;
  *(float4v*)(new2 + i4) = v;
  ushort4v o;
#pragma unroll
  for (int j = 0; j < 4; ++j) o[j] = f2bf(v[j]);
  *(ushort4v*)(new2bf + i4) = o;
}

// sparse correction: block b adds sum over flagged tiles (g,b) of
// sc1[g]*newm[m,g]*projW[n,g] to new2 rows of batch b; deterministic order.
__global__ __launch_bounds__(256) void corr_k(const int* __restrict__ cnt,
    const int* __restrict__ wl, const float* __restrict__ newm,
    const float* __restrict__ projw, const float* __restrict__ sc1,
    float* __restrict__ new2, u16* __restrict__ new2bf) {
  const int b = blockIdx.x, t = threadIdx.x;
  const int nf = *cnt;
  bool mine = false;
  for (int wi = 0; wi < nf; ++wi) if ((wl[wi] & 31) == b) { mine = true; break; }
  if (!mine) return;
  for (int m = 0; m < 196; ++m) {
    size_t row = ((size_t)b * 196 + m) * DIMC;
    for (int n = t; n < DIMC; n += 256) {
      float accv = 0.f;
      for (int wi = 0; wi < nf; ++wi) {
        int tile = wl[wi];
        if ((tile & 31) != b) continue;
        int g = tile >> 5;
        accv += sc1[g] * newm[row + g] * projw[(size_t)n * DIMC + g];
      }
      float nv = new2[row + n] + accv;
      new2[row + n] = nv;
      new2bf[row + n] = f2bf(nv);
    }
  }
}

// ---------------- 128x128 bf16 MFMA GEMM, BK=64, frag-ordered LDS ----------
// Single-buffer, 2 barriers/iter (R4 structure, proven correct/fastest), but
// BK=64: 8 gl16 + 32 MFMA per iter -> half the barrier-drain stalls.
// LDS chunk c (0..15): kslice s=c>>3, rowblk r=c&7; rows r*16..+15, k s*32..+31;
// in-chunk addr = lane*16B (linear, conflict-free).
// EPI 0: f32x4 transpose-write  vxt[(b*768+n)*196+np], m=b*196+np
// EPI 1: f32 C[m*Nr+n] = acc + bias[n] + res[m*Nr+n]
// EPI 2: bf16 C[m*Nr+n] = gelu_exact(acc + bias[n])
template<int EPI>
__global__ __launch_bounds__(256) void gemm_k(
    const u16* __restrict__ A, const u16* __restrict__ Bw,
    const float* __restrict__ bias, const float* __restrict__ res,
    void* __restrict__ Cp, int Nr, int Kr, int ld) {
  __shared__ __attribute__((aligned(16))) u16 As[128 * 64];
  __shared__ __attribute__((aligned(16))) u16 Bs[128 * 64];
  const int t = threadIdx.x;
  const int w = t >> 6, lane = t & 63;
  const int bn = blockIdx.x * 128, bm = blockIdx.y * 128;
  const int wm = (w >> 1) * 64, wn = (w & 1) * 64;
  const int l15 = lane & 15, l4 = lane >> 4;

  f32x4 acc[4][4];
#pragma unroll
  for (int a = 0; a < 4; ++a)
#pragma unroll
    for (int b2 = 0; b2 < 4; ++b2) acc[a][b2] = (f32x4){0.f, 0.f, 0.f, 0.f};

  // staging: wave w stages chunks c = w + 4*i (i=0..3) for both A and B
  const u16 *gA[4], *gB[4];
  int cc[4];
#pragma unroll
  for (int i = 0; i < 4; ++i) {
    int c = w + 4 * i;
    cc[i] = c;
    gA[i] = A + (size_t)(bm + (c & 7) * 16 + l15) * ld + (c >> 3) * 32 + l4 * 8;
    gB[i] = Bw + (size_t)(bn + (c & 7) * 16 + l15) * ld + (c >> 3) * 32 + l4 * 8;
  }

  const int nt = Kr >> 6;
  for (int kt = 0; kt < nt; ++kt) {
#pragma unroll
    for (int i = 0; i < 4; ++i) {
      gl16(gA[i] + kt * 64, &As[cc[i] * 512]);
      gl16(gB[i] + kt * 64, &Bs[cc[i] * 512]);
    }
    __syncthreads();

#pragma unroll
    for (int s = 0; s < 2; ++s) {
      bf16x8 af[4], bfv[4];
#pragma unroll
      for (int mb = 0; mb < 4; ++mb)
        af[mb] = *(const bf16x8*)&As[(s * 8 + (w >> 1) * 4 + mb) * 512 + lane * 8];
#pragma unroll
      for (int nb = 0; nb < 4; ++nb)
        bfv[nb] = *(const bf16x8*)&Bs[(s * 8 + (w & 1) * 4 + nb) * 512 + lane * 8];
#pragma unroll
      for (int mb = 0; mb < 4; ++mb)
#pragma unroll
        for (int nb = 0; nb < 4; ++nb)
          acc[mb][nb] = __builtin_amdgcn_mfma_f32_16x16x32_bf16(af[mb], bfv[nb], acc[mb][nb], 0, 0, 0);
    }
    __syncthreads();
  }

#pragma unroll
  for (int mb = 0; mb < 4; ++mb) {
#pragma unroll
    for (int nb = 0; nb < 4; ++nb) {
      int n = bn + wn + nb * 16 + l15;
      if (EPI == 0) {
        int m0 = bm + wm + mb * 16 + l4 * 4;
        int bb = m0 / 196, np0 = m0 - bb * 196;   // 4-aligned, same bb for r=0..3
        *(float4v*)&((float*)Cp)[((size_t)bb * DIMC + n) * 196 + np0] =
            (float4v){acc[mb][nb][0], acc[mb][nb][1], acc[mb][nb][2], acc[mb][nb][3]};
      } else {
#pragma unroll
        for (int r = 0; r < 4; ++r) {
          int m = bm + wm + mb * 16 + l4 * 4 + r;
          float v = acc[mb][nb][r];
          if (EPI == 1) {
            ((float*)Cp)[(size_t)m * Nr + n] = v + bias[n] + res[(size_t)m * Nr + n];
          } else {
            float vb = v + bias[n];
            float ge = 0.5f * vb * (1.f + erff(vb * 0.70710678118654752f));
            ((u16*)Cp)[(size_t)m * Nr + n] = f2bf(ge);
          }
        }
      }
    }
  }
}

// ---------------- BN stats (deterministic 2-stage) ----------------
__global__ __launch_bounds__(256) void stats_part_k(const float* __restrict__ A,
                                                    float* __restrict__ part) {
  int blk = blockIdx.x, t = threadIdx.x;
  float s0a = 0, s0b = 0, s0c = 0, s1a = 0, s1b = 0, s1c = 0;
  const float* base = A + (size_t)blk * 64 * DIMC;
  for (int r = 0; r < 64; ++r) {
    const float* row = base + (size_t)r * DIMC;
    float v0 = row[t], v1 = row[t + 256], v2 = row[t + 512];
    s0a += v0; s1a += v0 * v0;
    s0b += v1; s1b += v1 * v1;
    s0c += v2; s1c += v2 * v2;
  }
  part[(size_t)blk * DIMC + t] = s0a;
  part[(size_t)blk * DIMC + t + 256] = s0b;
  part[(size_t)blk * DIMC + t + 512] = s0c;
  float* p2 = part + 98 * DIMC;
  p2[(size_t)blk * DIMC + t] = s1a;
  p2[(size_t)blk * DIMC + t + 256] = s1b;
  p2[(size_t)blk * DIMC + t + 512] = s1c;
}

__global__ __launch_bounds__(256) void stats_fin_k(const float* __restrict__ part,
    const float* __restrict__ gam, const float* __restrict__ bet,
    float* __restrict__ scale, float* __restrict__ shift) {
  int c = blockIdx.x * 256 + threadIdx.x;
  if (c >= DIMC) return;
  float S = 0.f, Q = 0.f;
  for (int b = 0; b < 98; ++b) {
    S += part[(size_t)b * DIMC + c];
    Q += part[(size_t)(98 + b) * DIMC + c];
  }
  float m = S * (1.0f / 6272.0f);
  float v = Q * (1.0f / 6272.0f) - m * m;
  v = fmaxf(v, 0.f);
  float rs = rsqrtf(v + 1e-5f);
  float sc = gam[c] * rs;
  scale[c] = sc;
  shift[c] = bet[c] - m * sc;
}

// ---------------- MFMA screen: max_i max_p |u_i| per tile, flag > 3.4 ----------
__global__ __launch_bounds__(64) void checkmfma_k(
    const float* __restrict__ vxt, const float* __restrict__ kern,
    const u16* __restrict__ Ff, const u16* __restrict__ Gf,
    int* __restrict__ cnt, int* __restrict__ wl) {
  __shared__ float xf[16 * 228];
  const int lane = threadIdx.x;
  const int wgb = blockIdx.x;
  const int g = wgb >> 1, bhalf = wgb & 1;
  const int tl = lane & 15, h = lane >> 4;
  const float* xbase = vxt + ((size_t)(bhalf * 16 + tl) * DIMC + g) * 196;

  bf16x8 Bx[7];
#pragma unroll
  for (int k0 = 0; k0 < 7; ++k0) {
    int q0 = k0 * 32 + h * 8;
    ushort8v tv;
    if (k0 < 6) {
      float4v f0 = *(const float4v*)(xbase + q0);
      float4v f1 = *(const float4v*)(xbase + q0 + 4);
#pragma unroll
      for (int j = 0; j < 4; ++j) { tv[j] = f2bf(f0[j]); tv[j + 4] = f2bf(f1[j]); }
    } else {
#pragma unroll
      for (int j = 0; j < 8; ++j) {
        int q = q0 + j;
        tv[j] = (q < 196) ? f2bf(xbase[q]) : (u16)0;
      }
    }
    Bx[k0] = __builtin_bit_cast(bf16x8, tv);
  }

  for (int m0 = 0; m0 < 14; ++m0) {
    f32x4 acc = (f32x4){0.f, 0.f, 0.f, 0.f};
#pragma unroll
    for (int k0 = 0; k0 < 7; ++k0) {
      bf16x8 Af = __builtin_bit_cast(bf16x8,
          *(const ushort8v*)(Ff + ((size_t)(m0 * 7 + k0) * 64 + lane) * 8));
      acc = __builtin_amdgcn_mfma_f32_16x16x32_bf16(Af, Bx[k0], acc, 0, 0, 0);
    }
    *(f32x4*)&xf[tl * 228 + m0 * 16 + h * 4] = acc;
  }

  bf16x8 By[5][7];
#pragma unroll
  for (int i = 0; i < 5; ++i) {
    const float* kb = kern + ((size_t)g * 5 + i) * 224;
#pragma unroll
    for (int k0 = 0; k0 < 7; ++k0) {
      f32x4 x0 = *(const f32x4*)&xf[tl * 228 + k0 * 32 + h * 8];
      f32x4 x1 = *(const f32x4*)&xf[tl * 228 + k0 * 32 + h * 8 + 4];
      int mb = k0 * 16 + h * 4;
      float2 ka = *(const float2*)(kb + (mb + 0) * 2);
      float2 kc = *(const float2*)(kb + (mb + 1) * 2);
      float2 ke = *(const float2*)(kb + (mb + 2) * 2);
      float2 kg = *(const float2*)(kb + (mb + 3) * 2);
      ushort8v tv;
      tv[0] = f2bf(ka.x * x0[0] - ka.y * x0[1]);
      tv[1] = f2bf(ka.x * x0[1] + ka.y * x0[0]);
      tv[2] = f2bf(kc.x * x0[2] - kc.y * x0[3]);
      tv[3] = f2bf(kc.x * x0[3] + kc.y * x0[2]);
      tv[4] = f2bf(ke.x * x1[0] - ke.y * x1[1]);
      tv[5] = f2bf(ke.x * x1[1] + ke.y * x1[0]);
      tv[6] = f2bf(kg.x * x1[2] - kg.y * x1[3]);
      tv[7] = f2bf(kg.x * x1[3] + kg.y * x1[2]);
      By[i][k0] = __builtin_bit_cast(bf16x8, tv);
    }
  }

  float vmax = 0.f;
  for (int p0 = 0; p0 < 13; ++p0) {
    f32x4 a0 = (f32x4){0.f, 0.f, 0.f, 0.f};
    f32x4 a1 = a0, a2 = a0, a3 = a0, a4 = a0;
#pragma unroll
    for (int k0 = 0; k0 < 7; ++k0) {
      bf16x8 Ag = __builtin_bit_cast(bf16x8,
          *(const ushort8v*)(Gf + ((size_t)(p0 * 7 + k0) * 64 + lane) * 8));
      a0 = __builtin_amdgcn_mfma_f32_16x16x32_bf16(Ag, By[0][k0], a0, 0, 0, 0);
      a1 = __builtin_amdgcn_mfma_f32_16x16x32_bf16(Ag, By[1][k0], a1, 0, 0, 0);
      a2 = __builtin_amdgcn_mfma_f32_16x16x32_bf16(Ag, By[2][k0], a2, 0, 0, 0);
      a3 = __builtin_amdgcn_mfma_f32_16x16x32_bf16(Ag, By[3][k0], a3, 0, 0, 0);
      a4 = __builtin_amdgcn_mfma_f32_16x16x32_bf16(Ag, By[4][k0], a4, 0, 0, 0);
    }
#pragma unroll
    for (int r = 0; r < 4; ++r) {
      vmax = fmaxf(vmax, fabsf(a0[r]));
      vmax = fmaxf(vmax, fabsf(a1[r]));
      vmax = fmaxf(vmax, fabsf(a2[r]));
      vmax = fmaxf(vmax, fabsf(a3[r]));
      vmax = fmaxf(vmax, fabsf(a4[r]));
    }
  }
  vmax = fmaxf(vmax, __shfl_xor(vmax, 16));
  vmax = fmaxf(vmax, __shfl_xor(vmax, 32));
  if (lane < 16 && vmax > (LAMC - 0.1f)) {
    int idx = atomicAdd(cnt, 1);
    wl[idx] = g * 32 + bhalf * 16 + lane;
  }
}

// ---------------- full ISTA for flagged tiles (fp32, exact) ----------------
__global__ __launch_bounds__(64) void slow_k(
    const float* __restrict__ vxt, const float* __restrict__ kern,
    const float* __restrict__ kern2, const float* __restrict__ Lbuf,
    const int* __restrict__ cnt, const int* __restrict__ wl,
    float* __restrict__ outp) {
  const int t = threadIdx.x;
  __shared__ float TC[196], TSn[196];
  __shared__ float xs[196];
  __shared__ float t1R[112], t1I[112];
  __shared__ float t2R[112], t2I[112];
  __shared__ float zr[112], zi[112];
  __shared__ float kR[5][112], kI[5][112];
  __shared__ float uu[5][196];
  __shared__ float ss[5][196];
  __shared__ float k2R[112], k2I[112];

  for (int i = t; i < 196; i += 64) {
    int a = i / 14, c = i - (i / 14) * 14;
    int m = (a * c) % 14;
    TC[i] = C14d[m]; TSn[i] = S14d[m];
  }
  const int ntile = *cnt;

  auto rowsFwd = [&](const float* xsrc) {
    for (int i = t; i < 112; i += 64) {
      int r = i >> 3, f = i & 7;
      const float* xp = xsrc + r * 14;
      const float* tc = &TC[f * 14]; const float* tsn = &TSn[f * 14];
      float ar = 0.f, ai = 0.f;
#pragma unroll
      for (int c = 0; c < 14; ++c) { float xv = xp[c]; ar += xv * tc[c]; ai -= xv * tsn[c]; }
      t1R[i] = ar; t1I[i] = ai;
    }
    __syncthreads();
  };
  auto colsFwd = [&](float* oR, float* oI) {
    for (int i = t; i < 112; i += 64) {
      int kr = i >> 3, f = i & 7;
      const float* tc = &TC[kr * 14]; const float* tsn = &TSn[kr * 14];
      float br = 0.f, bi = 0.f;
#pragma unroll
      for (int r = 0; r < 14; ++r) {
        float xr = t1R[r * 8 + f], xi = t1I[r * 8 + f];
        br += tc[r] * xr + tsn[r] * xi;
        bi += tc[r] * xi - tsn[r] * xr;
      }
      oR[i] = br; oI[i] = bi;
    }
    __syncthreads();
  };
  auto colsInv = [&]() {
    for (int i = t; i < 112; i += 64) {
      int r = i >> 3, f = i & 7;
      const float* tc = &TC[r * 14]; const float* tsn = &TSn[r * 14];
      float br = 0.f, bi = 0.f;
#pragma unroll
      for (int kr = 0; kr < 14; ++kr) {
        float xr = t1R[kr * 8 + f], xi = t1I[kr * 8 + f];
        br += tc[kr] * xr - tsn[kr] * xi;
        bi += tc[kr] * xi + tsn[kr] * xr;
      }
      t2R[i] = br; t2I[i] = bi;
    }
    __syncthreads();
  };
  auto rowVal = [&](int r, int c) -> float {
    const float* pR = &t2R[r * 8]; const float* pI = &t2I[r * 8];
    float v = pR[0] + ((c & 1) ? -pR[7] : pR[7]);
    float s2 = 0.f;
#pragma unroll
    for (int f = 1; f < 7; ++f) s2 += pR[f] * TC[f * 14 + c] - pI[f] * TSn[f * 14 + c];
    return (v + 2.f * s2) * (1.0f / 196.0f);
  };

  for (int widx = blockIdx.x; widx < ntile; widx += gridDim.x) {
    const int tile = wl[widx];
    const int g = tile >> 5, b = tile & 31;
    __syncthreads();
    for (int i = t; i < 560; i += 64) {
      int ii = i / 112, p = i - ii * 112;
      const float* kp = kern + ((size_t)g * 5 + ii) * 224 + p * 2;
      kR[ii][p] = kp[0]; kI[ii][p] = kp[1];
    }
    for (int i = t; i < 196; i += 64) xs[i] = vxt[((size_t)b * DIMC + g) * 196 + i];
    for (int i = t; i < 112; i += 64) {
      k2R[i] = kern2[(size_t)g * 224 + i * 2];
      k2I[i] = kern2[(size_t)g * 224 + i * 2 + 1];
    }
    __syncthreads();

    rowsFwd(xs);
    colsFwd(zr, zi);
    for (int ii = 0; ii < 5; ++ii) {
      for (int i = t; i < 112; i += 64) {
        float a = kR[ii][i], b2 = kI[ii][i];
        t1R[i] = a * zr[i] - b2 * zi[i];
        t1I[i] = a * zi[i] + b2 * zr[i];
      }
      __syncthreads();
      colsInv();
      for (int i = t; i < 196; i += 64) uu[ii][i] = rowVal(i / 14, i - (i / 14) * 14);
      __syncthreads();
    }

    const float invL = 1.0f / Lbuf[g];
    const float thr = LAMC * invL;
    {
      float* up = &uu[0][0];
      float* sp = &ss[0][0];
      for (int i = t; i < 980; i += 64) {
        float v = up[i];
        float a = fabsf(v) - LAMC;
        sp[i] = a > 0.f ? copysignf(a, v) : 0.f;
      }
    }
    __syncthreads();

    for (int iter = 0; iter < 4; ++iter) {
      for (int i = t; i < 112; i += 64) { zr[i] = 0.f; zi[i] = 0.f; }
      __syncthreads();
      for (int ii = 0; ii < 5; ++ii) {
        rowsFwd(&ss[ii][0]);
        colsFwd(t2R, t2I);
        for (int i = t; i < 112; i += 64) {
          float a = kR[ii][i], b2 = kI[ii][i];
          zr[i] += a * t2R[i] + b2 * t2I[i];
          zi[i] += a * t2I[i] - b2 * t2R[i];
        }
        __syncthreads();
      }
      if (iter == 3) break;
      for (int ii = 0; ii < 5; ++ii) {
        for (int i = t; i < 112; i += 64) {
          float a = kR[ii][i], b2 = kI[ii][i];
          t1R[i] = a * zr[i] - b2 * zi[i];
          t1I[i] = a * zi[i] + b2 * zr[i];
        }
        __syncthreads();
        colsInv();
        for (int i = t; i < 196; i += 64) {
          float v = rowVal(i / 14, i - (i / 14) * 14);
          float sv = ss[ii][i] - (v - uu[ii][i]) * invL;
          float aa = fabsf(sv) - thr;
          ss[ii][i] = aa > 0.f ? copysignf(aa, sv) : 0.f;
        }
        __syncthreads();
      }
    }

    if (t < 28) {
      int kr = t >> 1, f = (t & 1) * 7;
      int d = kr * 8 + f;
      int srci = ((14 - kr) % 14) * 8 + f;
      float pr = 0.5f * (zr[d] + zr[srci]);
      float pi = 0.5f * (zi[d] - zi[srci]);
      zr[d] = pr; zi[d] = pi;
    }
    __syncthreads();
    for (int i = t; i < 112; i += 64) {
      float a = k2R[i], b2 = k2I[i];
      t1R[i] = a * zr[i] - b2 * zi[i];
      t1I[i] = a * zi[i] + b2 * zr[i];
    }
    __syncthreads();
    colsInv();
    for (int i = t; i < 196; i += 64)
      outp[((size_t)(b * 196 + i)) * DIMC + g] = rowVal(i / 14, i - (i / 14) * 14);
  }
}

// ---------------- launch ----------------
extern "C" void kernel_launch(void* const* d_in, const int* in_sizes, int n_in,
                              void* d_out, int out_size, void* d_ws, size_t ws_size,
                              hipStream_t stream) {
  (void)in_sizes; (void)n_in; (void)out_size;
  const float* x      = (const float*)d_in[0];
  const float* v_w    = (const float*)d_in[1];
  const float* proj_w = (const float*)d_in[2];
  const float* proj_b = (const float*)d_in[3];
  const float* kern   = (const float*)d_in[4];
  const float* kern2  = (const float*)d_in[5];
  const float* n1g    = (const float*)d_in[6];
  const float* n1b    = (const float*)d_in[7];
  const float* n2g    = (const float*)d_in[8];
  const float* n2b    = (const float*)d_in[9];
  const float* fc1w   = (const float*)d_in[10];
  const float* fc1b   = (const float*)d_in[11];
  const float* fc2w   = (const float*)d_in[12];
  const float* fc2b   = (const float*)d_in[13];
  const float* Lb     = (const float*)d_in[14];
  float* out = (float*)d_out;

  char* ws = (char*)d_ws;
  size_t o = 0;
  auto alloc = [&](size_t bytes) { size_t r = o; o += (bytes + 255) & ~(size_t)255; return r; };
  u16*   vwbf   = (u16*)(ws + alloc(589824 * 2));
  u16*   fc2bf  = (u16*)(ws + alloc(2359296 * 2));
  u16*   fc1s   = (u16*)(ws + alloc(2359296 * 2));
  u16*   Ffb    = (u16*)(ws + alloc(50176 * 2));
  u16*   Gfb    = (u16*)(ws + alloc(46592 * 2));
  float* sc1    = (float*)(ws + alloc(768 * 4));
  float* sh1    = (float*)(ws + alloc(768 * 4));
  float* sc2    = (float*)(ws + alloc(768 * 4));
  float* sh2    = (float*)(ws + alloc(768 * 4));
  float* c0     = (float*)(ws + alloc(768 * 4));
  float* d0     = (float*)(ws + alloc(3072 * 4));
  float* part   = (float*)(ws + alloc(98 * 768 * 2 * 4));
  int*   cnt    = (int*)(ws + alloc(4));
  int*   wl     = (int*)(ws + alloc(24576 * 4));
  u16*   xbf    = (u16*)(ws + alloc((size_t)MTOT * DIMC * 2));
  u16*   n2bf   = (u16*)(ws + alloc((size_t)MTOT * DIMC * 2));
  float* vxt    = (float*)(ws + alloc((size_t)MTOT * DIMC * 4));
  float* newm   = (float*)(ws + alloc((size_t)MTOT * DIMC * 4));
  float* new2   = (float*)(ws + alloc((size_t)MTOT * DIMC * 4));
  u16*   hbf    = (u16*)vxt;   // overlay: h (6272x3072 bf16 = 38.5 MB) over vxt+newm
                               // (vxt dead after slow_k, newm dead after corr_k)
  if (ws_size < o) return;

  hipMemsetAsync(newm, 0, (size_t)MTOT * DIMC * 4, stream);
  hipMemsetAsync(cnt, 0, 4, stream);

  initfg_k<<<378, 256, 0, stream>>>(Ffb, Gfb);
  cvtw2_k<<<2880, 256, 0, stream>>>(v_w, fc2w, vwbf, fc2bf);
  cvt4_k<<<4704, 256, 0, stream>>>(x, xbf, 1204224);

  // vx = x @ v_w^T, transpose-written as (b, g, n)
  gemm_k<0><<<dim3(6, 49), 256, 0, stream>>>(xbf, vwbf, nullptr, nullptr, vxt, DIMC, DIMC, DIMC);
  // MFMA screen -> worklist (newm stays zero for clean tiles)
  checkmfma_k<<<1536, 64, 0, stream>>>(vxt, kern, Ffb, Gfb, cnt, wl);
  // exact ISTA only for flagged tiles
  slow_k<<<1024, 64, 0, stream>>>(vxt, kern, kern2, Lb, cnt, wl, newm);
  // BN1 stats over newm (dense, mostly zero)
  stats_part_k<<<98, 256, 0, stream>>>(newm, part);
  stats_fin_k<<<3, 256, 0, stream>>>(part, n1g, n1b, sc1, sh1);
  // proj GEMM collapsed: c0 = projW @ sh1 + proj_b (f32 exact)
  c0_k<<<3, 256, 0, stream>>>(proj_w, sh1, proj_b, c0);
  // new2 = x + c0 (dense) -> f32 + bf16
  base_k<<<4704, 256, 0, stream>>>(x, c0, new2, n2bf);
  // + sparse correction from flagged tiles (deterministic per-batch)
  corr_k<<<32, 256, 0, stream>>>(cnt, wl, newm, proj_w, sc1, new2, n2bf);
  // BN2 stats
  stats_part_k<<<98, 256, 0, stream>>>(new2, part);
  stats_fin_k<<<3, 256, 0, stream>>>(part, n2g, n2b, sc2, sh2);
  // fold BN2 into fc1: fc1s = fc1w * sc2[k]; d0 = fc1w @ sh2 + fc1b
  d0_k<<<12, 256, 0, stream>>>(fc1w, sh2, fc1b, d0);
  scalefc1_k<<<2304, 256, 0, stream>>>(fc1w, sc2, fc1s);
  // h = gelu(new2 @ fc1s^T + d0)
  gemm_k<2><<<dim3(24, 49), 256, 0, stream>>>(n2bf, fc1s, d0, nullptr, hbf, HIDC, DIMC, DIMC);
  // out = new2 + h @ fc2^T + fc2_b
  gemm_k<1><<<dim3(6, 49), 256, 0, stream>>>(hbf, fc2bf, fc2b, new2, out, DIMC, HIDC, HIDC);
}

// Round 9
// 324.233 us; speedup vs baseline: 1.3602x; 1.1468x over previous
//
#include <hip/hip_runtime.h>
#include <cmath>

typedef unsigned short u16;
typedef __bf16 bf16x8 __attribute__((ext_vector_type(8)));
typedef float f32x4 __attribute__((ext_vector_type(4)));
typedef float float4v __attribute__((ext_vector_type(4)));
typedef u16 ushort4v __attribute__((ext_vector_type(4)));
typedef u16 ushort8v __attribute__((ext_vector_type(8)));

#define DIMC 768
#define NP 196
#define MTOT 6272         // 32*196
#define HIDC 3072
#define LAMC 3.5f

__device__ const float C14d[14] = {
  1.0f, 0.9009688679024191f, 0.6234898018587336f, 0.22252093395631445f,
  -0.22252093395631445f, -0.6234898018587336f, -0.9009688679024191f, -1.0f,
  -0.9009688679024191f, -0.6234898018587336f, -0.22252093395631445f,
  0.22252093395631445f, 0.6234898018587336f, 0.9009688679024191f
};
__device__ const float S14d[14] = {
  0.0f, 0.43388373911755823f, 0.7818314824680298f, 0.9749279121818236f,
  0.9749279121818236f, 0.7818314824680298f, 0.43388373911755823f, 0.0f,
  -0.43388373911755823f, -0.7818314824680298f, -0.9749279121818236f,
  -0.9749279121818236f, -0.7818314824680298f, -0.43388373911755823f
};

__device__ __forceinline__ u16 f2bf(float f) {
  unsigned u = __builtin_bit_cast(unsigned, f);
  unsigned r = u + 0x7FFFu + ((u >> 16) & 1u);
  return (u16)(r >> 16);
}

typedef const __attribute__((address_space(1))) u16* gas_p;
typedef __attribute__((address_space(3))) u16* las_p;
__device__ __forceinline__ void gl16(const u16* g, u16* l) {
  __builtin_amdgcn_global_load_lds((gas_p)g, (las_p)l, 16, 0, 0);
}

// ---------------- build fragment-ordered DFT matrices F / G ----------------
__global__ __launch_bounds__(256) void initfg_k(u16* __restrict__ Ff, u16* __restrict__ Gf) {
  int idx = blockIdx.x * 256 + threadIdx.x;
  if (idx < 50176) {                       // Ff: 14*7*64*8
    int j = idx & 7, lane = (idx >> 3) & 63;
    int mk = idx >> 9, k0 = mk % 7, m0 = mk / 7;
    int s = m0 * 16 + (lane & 15);
    int q = k0 * 32 + (lane >> 4) * 8 + j;
    float v = 0.f;
    if (q < 196) {
      int kr = s >> 4, f = (s >> 1) & 7, r = q / 14, c = q % 14;
      int th = (kr * r + f * c) % 14;
      v = (s & 1) ? -S14d[th] : C14d[th];
    }
    Ff[idx] = f2bf(v);
  } else if (idx < 50176 + 46592) {        // Gf: 13*7*64*8
    int t = idx - 50176;
    int j = t & 7, lane = (t >> 3) & 63;
    int pk = t >> 9, k0 = pk % 7, p0 = pk / 7;
    int p = p0 * 16 + (lane & 15);
    int s = k0 * 32 + (lane >> 4) * 8 + j;
    float v = 0.f;
    if (p < 196) {
      int kr = s >> 4, f = (s >> 1) & 7, r = p / 14, c = p % 14;
      int th = (kr * r + f * c) % 14;
      float w = (f == 0 || f == 7) ? 1.f : 2.f;
      v = (w * (1.f / 196.f)) * ((s & 1) ? -S14d[th] : C14d[th]);
    }
    Gf[t] = f2bf(v);
  }
}

// ---------------- weight converts ----------------
__global__ __launch_bounds__(256) void cvtw2_k(
    const float* __restrict__ w0, const float* __restrict__ w1,
    u16* __restrict__ o0, u16* __restrict__ o1) {
  int idx = blockIdx.x * 256 + threadIdx.x;
  const float* s; u16* d; int base;
  if (idx < 147456) { s = w0; d = o0; base = 0; }
  else              { s = w1; d = o1; base = 147456; }
  int i4 = (idx - base) * 4;
  float4v v = *(const float4v*)(s + i4);
  ushort4v o;
#pragma unroll
  for (int j = 0; j < 4; ++j) o[j] = f2bf(v[j]);
  *(ushort4v*)(d + i4) = o;
}

__global__ __launch_bounds__(256) void cvt4_k(const float* __restrict__ s,
                                              u16* __restrict__ d, int n4) {
  int idx = blockIdx.x * 256 + threadIdx.x;
  if (idx >= n4) return;
  int i4 = idx * 4;
  float4v v = *(const float4v*)(s + i4);
  ushort4v o;
#pragma unroll
  for (int j = 0; j < 4; ++j) o[j] = f2bf(v[j]);
  *(ushort4v*)(d + i4) = o;
}

// fc1s[n,k] = bf16(fc1w[n,k] * sc2[k])   (BN2 scale folded)
__global__ __launch_bounds__(256) void scalefc1_k(const float* __restrict__ w,
    const float* __restrict__ sc, u16* __restrict__ d) {
  int idx = blockIdx.x * 256 + threadIdx.x;
  int i4 = idx * 4;
  int k = i4 % DIMC;
  float4v v = *(const float4v*)(w + i4);
  float4v s = *(const float4v*)(sc + k);
  v = v * s;
  ushort4v o;
#pragma unroll
  for (int j = 0; j < 4; ++j) o[j] = f2bf(v[j]);
  *(ushort4v*)(d + i4) = o;
}

// c0[n] = proj_b[n] + sum_g sh1[g]*projW[n,g]
__global__ __launch_bounds__(256) void c0_k(const float* __restrict__ projw,
    const float* __restrict__ sh, const float* __restrict__ pb,
    float* __restrict__ c0) {
  int n = blockIdx.x * 256 + threadIdx.x;
  if (n >= DIMC) return;
  const float* row = projw + (size_t)n * DIMC;
  float s = 0.f;
  for (int g = 0; g < DIMC; g += 4) {
    float4v r = *(const float4v*)(row + g);
    float4v h = *(const float4v*)(sh + g);
    s += r[0] * h[0] + r[1] * h[1] + r[2] * h[2] + r[3] * h[3];
  }
  c0[n] = s + pb[n];
}

// d0[n] = fc1b[n] + sum_k sh2[k]*fc1w[n,k]
__global__ __launch_bounds__(256) void d0_k(const float* __restrict__ fc1w,
    const float* __restrict__ sh, const float* __restrict__ fb,
    float* __restrict__ d0) {
  int n = blockIdx.x * 256 + threadIdx.x;
  if (n >= HIDC) return;
  const float* row = fc1w + (size_t)n * DIMC;
  float s = 0.f;
  for (int k = 0; k < DIMC; k += 4) {
    float4v r = *(const float4v*)(row + k);
    float4v h = *(const float4v*)(sh + k);
    s += r[0] * h[0] + r[1] * h[1] + r[2] * h[2] + r[3] * h[3];
  }
  d0[n] = s + fb[n];
}

// new2 = x + c0 (dense base); writes f32 + bf16
__global__ __launch_bounds__(256) void base_k(const float* __restrict__ x,
    const float* __restrict__ c0, float* __restrict__ new2,
    u16* __restrict__ new2bf) {
  int idx = blockIdx.x * 256 + threadIdx.x;
  size_t i4 = (size_t)idx * 4;
  int c = (int)(i4 % DIMC);
  float4v v = *(const float4v*)(x + i4);
  float4v a = *(const float4v*)(c0 + c);
  v = v + a;
  *(float4v*)(new2 + i4) = v;
  ushort4v o;
#pragma unroll
  for (int j = 0; j < 4; ++j) o[j] = f2bf(v[j]);
  *(ushort4v*)(new2bf + i4) = o;
}

// per-flagged-tile sums of newm (for compact BN1 stats) + flag bitmasks
__global__ __launch_bounds__(64) void tilesum_k(const int* __restrict__ cnt,
    const int* __restrict__ wl, const float* __restrict__ newm,
    float* __restrict__ tsum, float* __restrict__ tsq,
    unsigned* __restrict__ maskg, unsigned* __restrict__ bmask) {
  const int nf = *cnt;
  const int lane = threadIdx.x;
  for (int wi = blockIdx.x; wi < nf; wi += gridDim.x) {
    int tile = wl[wi];
    int g = tile >> 5, b = tile & 31;
    float s = 0.f, q = 0.f;
    for (int m = lane; m < 196; m += 64) {
      float v = newm[((size_t)b * 196 + m) * DIMC + g];
      s += v; q += v * v;
    }
#pragma unroll
    for (int off = 32; off; off >>= 1) { s += __shfl_xor(s, off); q += __shfl_xor(q, off); }
    if (lane == 0) {
      tsum[tile] = s; tsq[tile] = q;
      atomicOr(&maskg[g], 1u << b);
      atomicOr(bmask, 1u << b);
    }
  }
}

// BN1 stats from tile sums (deterministic: ascending b)
__global__ __launch_bounds__(256) void stats1_fin_k(const float* __restrict__ tsum,
    const float* __restrict__ tsq, const unsigned* __restrict__ maskg,
    const float* __restrict__ gam, const float* __restrict__ bet,
    float* __restrict__ scale, float* __restrict__ shift) {
  int c = blockIdx.x * 256 + threadIdx.x;
  if (c >= DIMC) return;
  unsigned mask = maskg[c];
  float S = 0.f, Q = 0.f;
  for (int b = 0; b < 32; ++b)
    if ((mask >> b) & 1) { S += tsum[c * 32 + b]; Q += tsq[c * 32 + b]; }
  float m = S * (1.0f / 6272.0f);
  float v = Q * (1.0f / 6272.0f) - m * m;
  v = fmaxf(v, 0.f);
  float rs = rsqrtf(v + 1e-5f);
  float sc = gam[c] * rs;
  scale[c] = sc;
  shift[c] = bet[c] - m * sc;
}

// sparse correction (deterministic: ascending g via bitmask)
__global__ __launch_bounds__(256) void corr_k(const unsigned* __restrict__ maskg,
    const unsigned* __restrict__ bmask, const float* __restrict__ newm,
    const float* __restrict__ projw, const float* __restrict__ sc1,
    float* __restrict__ new2, u16* __restrict__ new2bf) {
  const int b = blockIdx.x, t = threadIdx.x;
  if (!((*bmask >> b) & 1)) return;
  __shared__ int gl[768];
  __shared__ int ngs;
  if (t == 0) {
    int n = 0;
    for (int g = 0; g < DIMC; ++g) if ((maskg[g] >> b) & 1) gl[n++] = g;
    ngs = n;
  }
  __syncthreads();
  const int n_g = ngs;
  for (int m = 0; m < 196; ++m) {
    size_t row = ((size_t)b * 196 + m) * DIMC;
    for (int n = t; n < DIMC; n += 256) {
      float a = 0.f;
      for (int i = 0; i < n_g; ++i) {
        int g = gl[i];
        a += sc1[g] * newm[row + g] * projw[(size_t)n * DIMC + g];
      }
      float nv = new2[row + n] + a;
      new2[row + n] = nv;
      new2bf[row + n] = f2bf(nv);
    }
  }
}

// ---------------- 128x128 bf16 MFMA GEMM (R3 body + XCD decode) ----------
// R3 structure: BK=32, 16 KB LDS/side, stage(4x gl16) -> sync -> 16 MFMA -> sync.
// XCD decode: xcd = bid&7; cols fastest within an XCD so a row's column-blocks
// share one L2 (A fetched ~once). Rows padded 49->56, dead blocks exit.
// EPI 0: f32x4 transpose-write  vxt[(b*768+n)*196+np], m=b*196+np
// EPI 1: f32 C[m*Nr+n] = acc + bias[n] + res[m*Nr+n]
// EPI 2: bf16 C[m*Nr+n] = gelu_exact(acc + bias[n])
template<int EPI>
__global__ __launch_bounds__(256) void gemm_k(
    const u16* __restrict__ A, const u16* __restrict__ Bw,
    const float* __restrict__ bias, const float* __restrict__ res,
    void* __restrict__ Cp, int Nr, int Kr, int ld, int NB) {
  __shared__ __attribute__((aligned(16))) u16 As[128 * 32];
  __shared__ __attribute__((aligned(16))) u16 Bs[128 * 32];
  const int t = threadIdx.x;
  const int wid = t >> 6, lane = t & 63;

  const int bid = blockIdx.x;
  const int xcd = bid & 7, j = bid >> 3;
  const int bmi = xcd + 8 * (j / NB);
  if (bmi >= 49) return;
  const int bn = (j % NB) * 128, bm = bmi * 128;

  const int wm = (wid >> 1) * 64, wn = (wid & 1) * 64;
  const int l15 = lane & 15, l4 = lane >> 4;
  const int srow = lane >> 2, scol = (lane & 3) * 8;

  f32x4 acc[4][4];
#pragma unroll
  for (int a = 0; a < 4; ++a)
#pragma unroll
    for (int b2 = 0; b2 < 4; ++b2) acc[a][b2] = (f32x4){0.f, 0.f, 0.f, 0.f};

  const u16* gA0 = A + (size_t)(bm + wid * 16 + srow) * ld + scol;
  const u16* gB0 = Bw + (size_t)(bn + wid * 16 + srow) * ld + scol;
  u16* lA = As + wid * 512;
  u16* lB = Bs + wid * 512;

  for (int k0 = 0; k0 < Kr; k0 += 32) {
    gl16(gA0 + k0, lA);
    gl16(gA0 + (size_t)64 * ld + k0, lA + 2048);
    gl16(gB0 + k0, lB);
    gl16(gB0 + (size_t)64 * ld + k0, lB + 2048);
    __syncthreads();

    bf16x8 af[4], bfv[4];
#pragma unroll
    for (int mb = 0; mb < 4; ++mb)
      af[mb] = *(const bf16x8*)&As[(wm + mb * 16 + l15) * 32 + l4 * 8];
#pragma unroll
    for (int nb = 0; nb < 4; ++nb)
      bfv[nb] = *(const bf16x8*)&Bs[(wn + nb * 16 + l15) * 32 + l4 * 8];
#pragma unroll
    for (int mb = 0; mb < 4; ++mb)
#pragma unroll
      for (int nb = 0; nb < 4; ++nb)
        acc[mb][nb] = __builtin_amdgcn_mfma_f32_16x16x32_bf16(af[mb], bfv[nb], acc[mb][nb], 0, 0, 0);
    __syncthreads();
  }

#pragma unroll
  for (int mb = 0; mb < 4; ++mb) {
#pragma unroll
    for (int nb = 0; nb < 4; ++nb) {
      int n = bn + wn + nb * 16 + l15;
      if (EPI == 0) {
        int m0 = bm + wm + mb * 16 + l4 * 4;
        int bb = m0 / 196, np0 = m0 - bb * 196;   // 4-aligned, same bb for r=0..3
        *(float4v*)&((float*)Cp)[((size_t)bb * DIMC + n) * 196 + np0] =
            (float4v){acc[mb][nb][0], acc[mb][nb][1], acc[mb][nb][2], acc[mb][nb][3]};
      } else {
#pragma unroll
        for (int r = 0; r < 4; ++r) {
          int m = bm + wm + mb * 16 + l4 * 4 + r;
          float v = acc[mb][nb][r];
          if (EPI == 1) {
            ((float*)Cp)[(size_t)m * Nr + n] = v + bias[n] + res[(size_t)m * Nr + n];
          } else {
            float vb = v + bias[n];
            float ge = 0.5f * vb * (1.f + erff(vb * 0.70710678118654752f));
            ((u16*)Cp)[(size_t)m * Nr + n] = f2bf(ge);
          }
        }
      }
    }
  }
}

// ---------------- BN2 stats (deterministic 2-stage, dense) ----------------
__global__ __launch_bounds__(256) void stats_part_k(const float* __restrict__ A,
                                                    float* __restrict__ part) {
  int blk = blockIdx.x, t = threadIdx.x;
  float s0a = 0, s0b = 0, s0c = 0, s1a = 0, s1b = 0, s1c = 0;
  const float* base = A + (size_t)blk * 64 * DIMC;
  for (int r = 0; r < 64; ++r) {
    const float* row = base + (size_t)r * DIMC;
    float v0 = row[t], v1 = row[t + 256], v2 = row[t + 512];
    s0a += v0; s1a += v0 * v0;
    s0b += v1; s1b += v1 * v1;
    s0c += v2; s1c += v2 * v2;
  }
  part[(size_t)blk * DIMC + t] = s0a;
  part[(size_t)blk * DIMC + t + 256] = s0b;
  part[(size_t)blk * DIMC + t + 512] = s0c;
  float* p2 = part + 98 * DIMC;
  p2[(size_t)blk * DIMC + t] = s1a;
  p2[(size_t)blk * DIMC + t + 256] = s1b;
  p2[(size_t)blk * DIMC + t + 512] = s1c;
}

__global__ __launch_bounds__(256) void stats_fin_k(const float* __restrict__ part,
    const float* __restrict__ gam, const float* __restrict__ bet,
    float* __restrict__ scale, float* __restrict__ shift) {
  int c = blockIdx.x * 256 + threadIdx.x;
  if (c >= DIMC) return;
  float S = 0.f, Q = 0.f;
  for (int b = 0; b < 98; ++b) {
    S += part[(size_t)b * DIMC + c];
    Q += part[(size_t)(98 + b) * DIMC + c];
  }
  float m = S * (1.0f / 6272.0f);
  float v = Q * (1.0f / 6272.0f) - m * m;
  v = fmaxf(v, 0.f);
  float rs = rsqrtf(v + 1e-5f);
  float sc = gam[c] * rs;
  scale[c] = sc;
  shift[c] = bet[c] - m * sc;
}

// ---------------- MFMA screen: max_i max_p |u_i| per tile, flag > 3.4 ----------
__global__ __launch_bounds__(64) void checkmfma_k(
    const float* __restrict__ vxt, const float* __restrict__ kern,
    const u16* __restrict__ Ff, const u16* __restrict__ Gf,
    int* __restrict__ cnt, int* __restrict__ wl) {
  __shared__ float xf[16 * 228];
  const int lane = threadIdx.x;
  const int wgb = blockIdx.x;
  const int g = wgb >> 1, bhalf = wgb & 1;
  const int tl = lane & 15, h = lane >> 4;
  const float* xbase = vxt + ((size_t)(bhalf * 16 + tl) * DIMC + g) * 196;

  bf16x8 Bx[7];
#pragma unroll
  for (int k0 = 0; k0 < 7; ++k0) {
    int q0 = k0 * 32 + h * 8;
    ushort8v tv;
    if (k0 < 6) {
      float4v f0 = *(const float4v*)(xbase + q0);
      float4v f1 = *(const float4v*)(xbase + q0 + 4);
#pragma unroll
      for (int j = 0; j < 4; ++j) { tv[j] = f2bf(f0[j]); tv[j + 4] = f2bf(f1[j]); }
    } else {
#pragma unroll
      for (int j = 0; j < 8; ++j) {
        int q = q0 + j;
        tv[j] = (q < 196) ? f2bf(xbase[q]) : (u16)0;
      }
    }
    Bx[k0] = __builtin_bit_cast(bf16x8, tv);
  }

  for (int m0 = 0; m0 < 14; ++m0) {
    f32x4 acc = (f32x4){0.f, 0.f, 0.f, 0.f};
#pragma unroll
    for (int k0 = 0; k0 < 7; ++k0) {
      bf16x8 Af = __builtin_bit_cast(bf16x8,
          *(const ushort8v*)(Ff + ((size_t)(m0 * 7 + k0) * 64 + lane) * 8));
      acc = __builtin_amdgcn_mfma_f32_16x16x32_bf16(Af, Bx[k0], acc, 0, 0, 0);
    }
    *(f32x4*)&xf[tl * 228 + m0 * 16 + h * 4] = acc;
  }

  bf16x8 By[5][7];
#pragma unroll
  for (int i = 0; i < 5; ++i) {
    const float* kb = kern + ((size_t)g * 5 + i) * 224;
#pragma unroll
    for (int k0 = 0; k0 < 7; ++k0) {
      f32x4 x0 = *(const f32x4*)&xf[tl * 228 + k0 * 32 + h * 8];
      f32x4 x1 = *(const f32x4*)&xf[tl * 228 + k0 * 32 + h * 8 + 4];
      int mb = k0 * 16 + h * 4;
      float2 ka = *(const float2*)(kb + (mb + 0) * 2);
      float2 kc = *(const float2*)(kb + (mb + 1) * 2);
      float2 ke = *(const float2*)(kb + (mb + 2) * 2);
      float2 kg = *(const float2*)(kb + (mb + 3) * 2);
      ushort8v tv;
      tv[0] = f2bf(ka.x * x0[0] - ka.y * x0[1]);
      tv[1] = f2bf(ka.x * x0[1] + ka.y * x0[0]);
      tv[2] = f2bf(kc.x * x0[2] - kc.y * x0[3]);
      tv[3] = f2bf(kc.x * x0[3] + kc.y * x0[2]);
      tv[4] = f2bf(ke.x * x1[0] - ke.y * x1[1]);
      tv[5] = f2bf(ke.x * x1[1] + ke.y * x1[0]);
      tv[6] = f2bf(kg.x * x1[2] - kg.y * x1[3]);
      tv[7] = f2bf(kg.x * x1[3] + kg.y * x1[2]);
      By[i][k0] = __builtin_bit_cast(bf16x8, tv);
    }
  }

  float vmax = 0.f;
  for (int p0 = 0; p0 < 13; ++p0) {
    f32x4 a0 = (f32x4){0.f, 0.f, 0.f, 0.f};
    f32x4 a1 = a0, a2 = a0, a3 = a0, a4 = a0;
#pragma unroll
    for (int k0 = 0; k0 < 7; ++k0) {
      bf16x8 Ag = __builtin_bit_cast(bf16x8,
          *(const ushort8v*)(Gf + ((size_t)(p0 * 7 + k0) * 64 + lane) * 8));
      a0 = __builtin_amdgcn_mfma_f32_16x16x32_bf16(Ag, By[0][k0], a0, 0, 0, 0);
      a1 = __builtin_amdgcn_mfma_f32_16x16x32_bf16(Ag, By[1][k0], a1, 0, 0, 0);
      a2 = __builtin_amdgcn_mfma_f32_16x16x32_bf16(Ag, By[2][k0], a2, 0, 0, 0);
      a3 = __builtin_amdgcn_mfma_f32_16x16x32_bf16(Ag, By[3][k0], a3, 0, 0, 0);
      a4 = __builtin_amdgcn_mfma_f32_16x16x32_bf16(Ag, By[4][k0], a4, 0, 0, 0);
    }
#pragma unroll
    for (int r = 0; r < 4; ++r) {
      vmax = fmaxf(vmax, fabsf(a0[r]));
      vmax = fmaxf(vmax, fabsf(a1[r]));
      vmax = fmaxf(vmax, fabsf(a2[r]));
      vmax = fmaxf(vmax, fabsf(a3[r]));
      vmax = fmaxf(vmax, fabsf(a4[r]));
    }
  }
  vmax = fmaxf(vmax, __shfl_xor(vmax, 16));
  vmax = fmaxf(vmax, __shfl_xor(vmax, 32));
  if (lane < 16 && vmax > (LAMC - 0.1f)) {
    int idx = atomicAdd(cnt, 1);
    wl[idx] = g * 32 + bhalf * 16 + lane;
  }
}

// ---------------- full ISTA for flagged tiles (fp32, exact) ----------------
__global__ __launch_bounds__(64) void slow_k(
    const float* __restrict__ vxt, const float* __restrict__ kern,
    const float* __restrict__ kern2, const float* __restrict__ Lbuf,
    const int* __restrict__ cnt, const int* __restrict__ wl,
    float* __restrict__ outp) {
  const int t = threadIdx.x;
  __shared__ float TC[196], TSn[196];
  __shared__ float xs[196];
  __shared__ float t1R[112], t1I[112];
  __shared__ float t2R[112], t2I[112];
  __shared__ float zr[112], zi[112];
  __shared__ float kR[5][112], kI[5][112];
  __shared__ float uu[5][196];
  __shared__ float ss[5][196];
  __shared__ float k2R[112], k2I[112];

  for (int i = t; i < 196; i += 64) {
    int a = i / 14, c = i - (i / 14) * 14;
    int m = (a * c) % 14;
    TC[i] = C14d[m]; TSn[i] = S14d[m];
  }
  const int ntile = *cnt;

  auto rowsFwd = [&](const float* xsrc) {
    for (int i = t; i < 112; i += 64) {
      int r = i >> 3, f = i & 7;
      const float* xp = xsrc + r * 14;
      const float* tc = &TC[f * 14]; const float* tsn = &TSn[f * 14];
      float ar = 0.f, ai = 0.f;
#pragma unroll
      for (int c = 0; c < 14; ++c) { float xv = xp[c]; ar += xv * tc[c]; ai -= xv * tsn[c]; }
      t1R[i] = ar; t1I[i] = ai;
    }
    __syncthreads();
  };
  auto colsFwd = [&](float* oR, float* oI) {
    for (int i = t; i < 112; i += 64) {
      int kr = i >> 3, f = i & 7;
      const float* tc = &TC[kr * 14]; const float* tsn = &TSn[kr * 14];
      float br = 0.f, bi = 0.f;
#pragma unroll
      for (int r = 0; r < 14; ++r) {
        float xr = t1R[r * 8 + f], xi = t1I[r * 8 + f];
        br += tc[r] * xr + tsn[r] * xi;
        bi += tc[r] * xi - tsn[r] * xr;
      }
      oR[i] = br; oI[i] = bi;
    }
    __syncthreads();
  };
  auto colsInv = [&]() {
    for (int i = t; i < 112; i += 64) {
      int r = i >> 3, f = i & 7;
      const float* tc = &TC[r * 14]; const float* tsn = &TSn[r * 14];
      float br = 0.f, bi = 0.f;
#pragma unroll
      for (int kr = 0; kr < 14; ++kr) {
        float xr = t1R[kr * 8 + f], xi = t1I[kr * 8 + f];
        br += tc[kr] * xr - tsn[kr] * xi;
        bi += tc[kr] * xi + tsn[kr] * xr;
      }
      t2R[i] = br; t2I[i] = bi;
    }
    __syncthreads();
  };
  auto rowVal = [&](int r, int c) -> float {
    const float* pR = &t2R[r * 8]; const float* pI = &t2I[r * 8];
    float v = pR[0] + ((c & 1) ? -pR[7] : pR[7]);
    float s2 = 0.f;
#pragma unroll
    for (int f = 1; f < 7; ++f) s2 += pR[f] * TC[f * 14 + c] - pI[f] * TSn[f * 14 + c];
    return (v + 2.f * s2) * (1.0f / 196.0f);
  };

  for (int widx = blockIdx.x; widx < ntile; widx += gridDim.x) {
    const int tile = wl[widx];
    const int g = tile >> 5, b = tile & 31;
    __syncthreads();
    for (int i = t; i < 560; i += 64) {
      int ii = i / 112, p = i - ii * 112;
      const float* kp = kern + ((size_t)g * 5 + ii) * 224 + p * 2;
      kR[ii][p] = kp[0]; kI[ii][p] = kp[1];
    }
    for (int i = t; i < 196; i += 64) xs[i] = vxt[((size_t)b * DIMC + g) * 196 + i];
    for (int i = t; i < 112; i += 64) {
      k2R[i] = kern2[(size_t)g * 224 + i * 2];
      k2I[i] = kern2[(size_t)g * 224 + i * 2 + 1];
    }
    __syncthreads();

    rowsFwd(xs);
    colsFwd(zr, zi);
    for (int ii = 0; ii < 5; ++ii) {
      for (int i = t; i < 112; i += 64) {
        float a = kR[ii][i], b2 = kI[ii][i];
        t1R[i] = a * zr[i] - b2 * zi[i];
        t1I[i] = a * zi[i] + b2 * zr[i];
      }
      __syncthreads();
      colsInv();
      for (int i = t; i < 196; i += 64) uu[ii][i] = rowVal(i / 14, i - (i / 14) * 14);
      __syncthreads();
    }

    const float invL = 1.0f / Lbuf[g];
    const float thr = LAMC * invL;
    {
      float* up = &uu[0][0];
      float* sp = &ss[0][0];
      for (int i = t; i < 980; i += 64) {
        float v = up[i];
        float a = fabsf(v) - LAMC;
        sp[i] = a > 0.f ? copysignf(a, v) : 0.f;
      }
    }
    __syncthreads();

    for (int iter = 0; iter < 4; ++iter) {
      for (int i = t; i < 112; i += 64) { zr[i] = 0.f; zi[i] = 0.f; }
      __syncthreads();
      for (int ii = 0; ii < 5; ++ii) {
        rowsFwd(&ss[ii][0]);
        colsFwd(t2R, t2I);
        for (int i = t; i < 112; i += 64) {
          float a = kR[ii][i], b2 = kI[ii][i];
          zr[i] += a * t2R[i] + b2 * t2I[i];
          zi[i] += a * t2I[i] - b2 * t2R[i];
        }
        __syncthreads();
      }
      if (iter == 3) break;
      for (int ii = 0; ii < 5; ++ii) {
        for (int i = t; i < 112; i += 64) {
          float a = kR[ii][i], b2 = kI[ii][i];
          t1R[i] = a * zr[i] - b2 * zi[i];
          t1I[i] = a * zi[i] + b2 * zr[i];
        }
        __syncthreads();
        colsInv();
        for (int i = t; i < 196; i += 64) {
          float v = rowVal(i / 14, i - (i / 14) * 14);
          float sv = ss[ii][i] - (v - uu[ii][i]) * invL;
          float aa = fabsf(sv) - thr;
          ss[ii][i] = aa > 0.f ? copysignf(aa, sv) : 0.f;
        }
        __syncthreads();
      }
    }

    if (t < 28) {
      int kr = t >> 1, f = (t & 1) * 7;
      int d = kr * 8 + f;
      int srci = ((14 - kr) % 14) * 8 + f;
      float pr = 0.5f * (zr[d] + zr[srci]);
      float pi = 0.5f * (zi[d] - zi[srci]);
      zr[d] = pr; zi[d] = pi;
    }
    __syncthreads();
    for (int i = t; i < 112; i += 64) {
      float a = k2R[i], b2 = k2I[i];
      t1R[i] = a * zr[i] - b2 * zi[i];
      t1I[i] = a * zi[i] + b2 * zr[i];
    }
    __syncthreads();
    colsInv();
    for (int i = t; i < 196; i += 64)
      outp[((size_t)(b * 196 + i)) * DIMC + g] = rowVal(i / 14, i - (i / 14) * 14);
  }
}

// ---------------- launch ----------------
extern "C" void kernel_launch(void* const* d_in, const int* in_sizes, int n_in,
                              void* d_out, int out_size, void* d_ws, size_t ws_size,
                              hipStream_t stream) {
  (void)in_sizes; (void)n_in; (void)out_size;
  const float* x      = (const float*)d_in[0];
  const float* v_w    = (const float*)d_in[1];
  const float* proj_w = (const float*)d_in[2];
  const float* proj_b = (const float*)d_in[3];
  const float* kern   = (const float*)d_in[4];
  const float* kern2  = (const float*)d_in[5];
  const float* n1g    = (const float*)d_in[6];
  const float* n1b    = (const float*)d_in[7];
  const float* n2g    = (const float*)d_in[8];
  const float* n2b    = (const float*)d_in[9];
  const float* fc1w   = (const float*)d_in[10];
  const float* fc1b   = (const float*)d_in[11];
  const float* fc2w   = (const float*)d_in[12];
  const float* fc2b   = (const float*)d_in[13];
  const float* Lb     = (const float*)d_in[14];
  float* out = (float*)d_out;

  char* ws = (char*)d_ws;
  size_t o = 0;
  auto alloc = [&](size_t bytes) { size_t r = o; o += (bytes + 255) & ~(size_t)255; return r; };
  u16*   vwbf   = (u16*)(ws + alloc(589824 * 2));
  u16*   fc2bf  = (u16*)(ws + alloc(2359296 * 2));
  u16*   fc1s   = (u16*)(ws + alloc(2359296 * 2));
  u16*   Ffb    = (u16*)(ws + alloc(50176 * 2));
  u16*   Gfb    = (u16*)(ws + alloc(46592 * 2));
  float* sc1    = (float*)(ws + alloc(768 * 4));
  float* sh1    = (float*)(ws + alloc(768 * 4));
  float* sc2    = (float*)(ws + alloc(768 * 4));
  float* sh2    = (float*)(ws + alloc(768 * 4));
  float* c0     = (float*)(ws + alloc(768 * 4));
  float* d0     = (float*)(ws + alloc(3072 * 4));
  float* part   = (float*)(ws + alloc(98 * 768 * 2 * 4));
  char*  zblk   = (char*)(ws + alloc(4096));       // cnt(4) | bmask(4) | maskg(3072)
  int*      cnt   = (int*)zblk;
  unsigned* bmask = (unsigned*)(zblk + 4);
  unsigned* maskg = (unsigned*)(zblk + 8);
  int*   wl     = (int*)(ws + alloc(24576 * 4));
  float* tsum   = (float*)(ws + alloc(24576 * 4));
  float* tsq    = (float*)(ws + alloc(24576 * 4));
  u16*   xbf    = (u16*)(ws + alloc((size_t)MTOT * DIMC * 2));
  u16*   n2bf   = (u16*)(ws + alloc((size_t)MTOT * DIMC * 2));
  float* vxt    = (float*)(ws + alloc((size_t)MTOT * DIMC * 4));
  float* newm   = (float*)(ws + alloc((size_t)MTOT * DIMC * 4));
  float* new2   = (float*)(ws + alloc((size_t)MTOT * DIMC * 4));
  u16*   hbf    = (u16*)vxt;   // overlay: h (38.5 MB) over vxt+newm (both dead by fc1)
  if (ws_size < o) return;

  hipMemsetAsync(zblk, 0, 4096, stream);

  initfg_k<<<378, 256, 0, stream>>>(Ffb, Gfb);
  cvtw2_k<<<2880, 256, 0, stream>>>(v_w, fc2w, vwbf, fc2bf);
  cvt4_k<<<4704, 256, 0, stream>>>(x, xbf, 1204224);

  // vx = x @ v_w^T, transpose-written as (b, g, n)   grid 8*6*7
  gemm_k<0><<<336, 256, 0, stream>>>(xbf, vwbf, nullptr, nullptr, vxt, DIMC, DIMC, DIMC, 6);
  // MFMA screen -> worklist
  checkmfma_k<<<1536, 64, 0, stream>>>(vxt, kern, Ffb, Gfb, cnt, wl);
  // exact ISTA only for flagged tiles (newm read only at flagged positions)
  slow_k<<<1024, 64, 0, stream>>>(vxt, kern, kern2, Lb, cnt, wl, newm);
  // compact BN1 stats from flagged tiles only
  tilesum_k<<<256, 64, 0, stream>>>(cnt, wl, newm, tsum, tsq, maskg, bmask);
  stats1_fin_k<<<3, 256, 0, stream>>>(tsum, tsq, maskg, n1g, n1b, sc1, sh1);
  // proj GEMM collapsed: c0 = projW @ sh1 + proj_b
  c0_k<<<3, 256, 0, stream>>>(proj_w, sh1, proj_b, c0);
  // new2 = x + c0 (dense) -> f32 + bf16, then sparse low-rank correction
  base_k<<<4704, 256, 0, stream>>>(x, c0, new2, n2bf);
  corr_k<<<32, 256, 0, stream>>>(maskg, bmask, newm, proj_w, sc1, new2, n2bf);
  // BN2 stats (dense)
  stats_part_k<<<98, 256, 0, stream>>>(new2, part);
  stats_fin_k<<<3, 256, 0, stream>>>(part, n2g, n2b, sc2, sh2);
  // fold BN2 into fc1
  d0_k<<<12, 256, 0, stream>>>(fc1w, sh2, fc1b, d0);
  scalefc1_k<<<2304, 256, 0, stream>>>(fc1w, sc2, fc1s);
  // h = gelu(new2 @ fc1s^T + d0)   grid 8*24*7
  gemm_k<2><<<1344, 256, 0, stream>>>(n2bf, fc1s, d0, nullptr, hbf, HIDC, DIMC, DIMC, 24);
  // out = new2 + h @ fc2^T + fc2_b   grid 8*6*7
  gemm_k<1><<<336, 256, 0, stream>>>(hbf, fc2bf, fc2b, new2, out, DIMC, HIDC, HIDC, 6);
}